// Round 1
// baseline (424.945 us; speedup 1.0000x reference)
//
#include <hip/hip_runtime.h>

// MultiHeadAttention: B=8, C=256, H=8, D=32, T=16, P=1024, F=D*T=512
// Pipeline:
//  k_wconv : Wk/Wq/Wv fp32 -> bf16 (Wbf[3][256][256])
//  k_proj  : y = W @ x for all 3 projections; writes Kb,Qb as [bh][p][512] bf16,
//            V transposed as Vt [bh][f][1024] bf16. All with 16B-chunk XOR pre-swizzle.
//  k_egemm : Pt[bh][q][p] = bf16( exp2( (Q.K^T) * log2e/sqrt(512) ) )   (unnormalized)
//  k_colsum/k_zfinal : Z[p] = sum_q Pt[q][p]; RZ = 1/Z   (deterministic, q-split x8)
//  k_vscale: Vt[f][p] *= RZ[p]  in-place (regenerated every call by k_proj)
//  k_pv    : out[q][f] = sum_p Pt[q,p] * Vt'[f,p]  -> d_out fp32 [B,C,P,T]
// ws usage ~323 MB.

typedef unsigned short u16;
typedef unsigned int u32;
typedef __attribute__((ext_vector_type(8))) short bfx8;
typedef __attribute__((ext_vector_type(4))) float fx4;

constexpr float KC1 = 1.4426950408889634f / 22.627416997969522f; // log2(e)/sqrt(512)

__device__ __forceinline__ u16 f2bf(float f) {
  u32 u = __builtin_bit_cast(u32, f);
  return (u16)((u + 0x7fffu + ((u >> 16) & 1u)) >> 16);
}
__device__ __forceinline__ float bf2f(u16 v) {
  return __builtin_bit_cast(float, (u32)v << 16);
}
__device__ __forceinline__ fx4 mfma16(bfx8 a, bfx8 b, fx4 c) {
  return __builtin_amdgcn_mfma_f32_16x16x32_bf16(a, b, c, 0, 0, 0);
}

typedef __attribute__((address_space(1))) const unsigned int* as1p;
typedef __attribute__((address_space(3))) unsigned int* as3p;
__device__ __forceinline__ void gll16(const void* g, void* l) {
  __builtin_amdgcn_global_load_lds((as1p)g, (as3p)l, 16, 0, 0);
}

// ---------------- W fp32 -> bf16 ----------------
__global__ __launch_bounds__(256) void k_wconv(const float* __restrict__ Wk,
                                               const float* __restrict__ Wq,
                                               const float* __restrict__ Wv,
                                               u16* __restrict__ Wbf) {
  int blk = blockIdx.x;          // 96
  int w = blk >> 5;              // 0..2
  const float* src = (w == 0) ? Wk : ((w == 1) ? Wq : Wv);
  int base = (blk & 31) * 2048 + threadIdx.x * 8;
  const float4* s4 = (const float4*)(src + base);
  float4 a = s4[0], b = s4[1];
  alignas(16) u16 t[8] = {f2bf(a.x), f2bf(a.y), f2bf(a.z), f2bf(a.w),
                          f2bf(b.x), f2bf(b.y), f2bf(b.z), f2bf(b.w)};
  *(uint4*)(Wbf + w * 65536 + base) = *(const uint4*)t;
}

// ---------------- fused projection ----------------
// grid 1024 (b * 128 ntiles), 256 thr. M=256(o) x N=128(n=p*16+t) x K=256(c).
__global__ __launch_bounds__(256) void k_proj(const float* __restrict__ x,
                                              const u16* __restrict__ Wbf,
                                              u16* __restrict__ Kb, u16* __restrict__ Qb,
                                              u16* __restrict__ Vt) {
  __shared__ u16 Xs[128 * 256]; // [n_local][c] bf16, chunk^=(n&7); reused as Vlds[8][512][8]
  int vid = (blockIdx.x & 7) * 128 + (blockIdx.x >> 3);
  int b = vid >> 7;
  int ntile = vid & 127;
  int n0 = ntile * 128;
  int tid = threadIdx.x, lane = tid & 63, wv = tid >> 6;
  int l15 = lane & 15, kg = lane >> 4, l7 = lane & 7;

  { // stage X tile: fp32 -> bf16, transpose to [n][c]
    int nl = tid & 127;
    int cg = (tid >> 7) * 4; // 0 or 4
    const float* xb = x + (size_t)b * 4194304 + n0 + nl;
    int nl7 = nl & 7;
#pragma unroll 4
    for (int i = 0; i < 32; ++i) {
      int c = cg + i * 8;
      float f0 = xb[(size_t)c * 16384];
      float f1 = xb[(size_t)(c + 1) * 16384];
      float f2 = xb[(size_t)(c + 2) * 16384];
      float f3 = xb[(size_t)(c + 3) * 16384];
      alignas(8) u16 t[4] = {f2bf(f0), f2bf(f1), f2bf(f2), f2bf(f3)};
      int sw = ((c >> 3) ^ nl7) * 8 + (c & 7);
      *(unsigned long long*)&Xs[nl * 256 + sw] = *(const unsigned long long*)t;
    }
  }
  __syncthreads();

  int mbase = wv * 64;
  fx4 acc[4][8];
  for (int pr = 0; pr < 3; ++pr) {
#pragma unroll
    for (int mt = 0; mt < 4; ++mt)
#pragma unroll
      for (int nt = 0; nt < 8; ++nt) acc[mt][nt] = (fx4)0.0f;
    const u16* Wp = Wbf + pr * 65536;
    for (int ks = 0; ks < 8; ++ks) {
      bfx8 af[4];
      const u16* wsrc = Wp + ks * 32 + kg * 8;
#pragma unroll
      for (int mt = 0; mt < 4; ++mt)
        af[mt] = *(const bfx8*)(wsrc + (mbase + mt * 16 + l15) * 256);
      int csw = ((ks * 4 + kg) ^ l7) * 8;
#pragma unroll
      for (int nt = 0; nt < 8; ++nt) {
        bfx8 bf = *(const bfx8*)&Xs[(nt * 16 + l15) * 256 + csw];
#pragma unroll
        for (int mt = 0; mt < 4; ++mt) acc[mt][nt] = mfma16(af[mt], bf, acc[mt][nt]);
      }
    }
    if (pr < 2) {
      u16* dst = (pr == 0) ? Kb : Qb;
#pragma unroll
      for (int mt = 0; mt < 4; ++mt) {
        int o = mbase + mt * 16;
        int bh = b * 8 + (o >> 5);
        int d0 = (o & 31) + kg * 4;
#pragma unroll
        for (int nt = 0; nt < 8; ++nt) {
          int p = ntile * 8 + nt;
          size_t ro = (size_t)bh * 524288 + (size_t)p * 512;
#pragma unroll
          for (int j = 0; j < 4; ++j) {
            int f = (d0 + j) * 16 + l15;
            int ch = (f >> 3) ^ (p & 7);
            dst[ro + ch * 8 + (f & 7)] = f2bf(acc[mt][nt][j]);
          }
        }
      }
    } else {
      __syncthreads(); // all waves done reading Xs
      u16* Vl = Xs;    // [8 h][512 f][8 p]
#pragma unroll
      for (int mt = 0; mt < 4; ++mt) {
        int o = mbase + mt * 16;
        int h = o >> 5;
        int d0 = (o & 31) + kg * 4;
#pragma unroll
        for (int nt = 0; nt < 8; ++nt)
#pragma unroll
          for (int j = 0; j < 4; ++j) {
            int f = (d0 + j) * 16 + l15;
            Vl[h * 4096 + f * 8 + nt] = f2bf(acc[mt][nt][j]);
          }
      }
      __syncthreads();
#pragma unroll 2
      for (int i = 0; i < 16; ++i) {
        int hf = tid + i * 256;
        int f = hf & 511;
        int bh = b * 8 + (hf >> 9);
        uint4 v = *(const uint4*)&Vl[hf * 8];
        *(uint4*)&Vt[(size_t)bh * 524288 + (size_t)f * 1024 + (size_t)(ntile ^ (f & 7)) * 8] = v;
      }
    }
  }
}

// ---------------- E-GEMM + exp2 -> Pt ----------------
// grid 1024 (bh x 16 tiles), 512 thr. 256x256 tile, BK=64, wave-tile 128x64.
__global__ __launch_bounds__(512) void k_egemm(const u16* __restrict__ Qb,
                                               const u16* __restrict__ Kb,
                                               u16* __restrict__ Pt) {
  __shared__ u16 As[256 * 64];
  __shared__ u16 Bs[256 * 64];
  int vid = (blockIdx.x & 7) * 128 + (blockIdx.x >> 3);
  int bh = vid >> 4;
  int tile = vid & 15;
  int q0 = (tile >> 2) * 256, p0 = (tile & 3) * 256;
  int tid = threadIdx.x, lane = tid & 63, wv = tid >> 6;
  int l15 = lane & 15, kg = lane >> 4, l7 = lane & 7;
  int wq0 = (wv >> 2) * 128, wp0 = (wv & 3) * 64;
  const u16* Arow = Qb + (size_t)bh * 524288 + (size_t)q0 * 512;
  const u16* Brow = Kb + (size_t)bh * 524288 + (size_t)p0 * 512;
  int rsub = lane >> 3, csub = (lane & 7) * 8;
  fx4 acc[8][4];
#pragma unroll
  for (int mt = 0; mt < 8; ++mt)
#pragma unroll
    for (int nt = 0; nt < 4; ++nt) acc[mt][nt] = (fx4)0.0f;

  for (int ks = 0; ks < 8; ++ks) {
    __syncthreads();
#pragma unroll
    for (int i = 0; i < 4; ++i) {
      int r = wv * 32 + i * 8;
      gll16(Arow + (size_t)(r + rsub) * 512 + ks * 64 + csub, As + r * 64);
      gll16(Brow + (size_t)(r + rsub) * 512 + ks * 64 + csub, Bs + r * 64);
    }
    __syncthreads();
#pragma unroll
    for (int kk = 0; kk < 2; ++kk) {
      int csw = ((kk * 4 + kg) ^ l7) * 8;
      bfx8 af[8];
#pragma unroll
      for (int mt = 0; mt < 8; ++mt)
        af[mt] = *(const bfx8*)&As[(wq0 + mt * 16 + l15) * 64 + csw];
#pragma unroll
      for (int nt = 0; nt < 4; ++nt) {
        bfx8 bf = *(const bfx8*)&Bs[(wp0 + nt * 16 + l15) * 64 + csw];
#pragma unroll
        for (int mt = 0; mt < 8; ++mt) acc[mt][nt] = mfma16(af[mt], bf, acc[mt][nt]);
      }
    }
  }
  size_t pbase = (size_t)bh * 1048576;
#pragma unroll
  for (int mt = 0; mt < 8; ++mt) {
    int qb_ = q0 + wq0 + mt * 16 + kg * 4;
#pragma unroll
    for (int nt = 0; nt < 4; ++nt) {
      int p = p0 + wp0 + nt * 16 + l15;
#pragma unroll
      for (int j = 0; j < 4; ++j) {
        int q = qb_ + j;
        Pt[pbase + (size_t)q * 1024 + (((p >> 3) ^ (q & 7)) * 8 + (p & 7))] =
            f2bf(exp2f(acc[mt][nt][j] * KC1));
      }
    }
  }
}

// ---------------- column sums of Pt over q ----------------
__global__ __launch_bounds__(256) void k_colsum(const u16* __restrict__ Pt,
                                                float* __restrict__ Zpart) {
  int blk = blockIdx.x;          // 1024 = 8 qq * 64 bh * 2 pb
  int qq = blk >> 7, bh = (blk >> 1) & 63, pb = blk & 1;
  int p = pb * 512 + threadIdx.x * 2;
  const u16* base = Pt + (size_t)bh * 1048576 + (size_t)qq * 131072;
  int pc = p >> 3, pl = p & 7;
  int offs[8];
#pragma unroll
  for (int qo = 0; qo < 8; ++qo) offs[qo] = qo * 1024 + ((pc ^ qo) * 8) + pl;
  float s0 = 0.f, s1 = 0.f;
  for (int q8 = 0; q8 < 16; ++q8) {
#pragma unroll
    for (int qo = 0; qo < 8; ++qo) {
      u32 v = *(const u32*)&base[offs[qo]];
      s0 += bf2f((u16)v);
      s1 += bf2f((u16)(v >> 16));
    }
    base += 8192;
  }
  Zpart[(size_t)qq * 65536 + bh * 1024 + p] = s0;
  Zpart[(size_t)qq * 65536 + bh * 1024 + p + 1] = s1;
}

__global__ __launch_bounds__(256) void k_zfinal(const float* __restrict__ Zpart,
                                                float* __restrict__ RZ) {
  int idx = blockIdx.x * 256 + threadIdx.x; // 65536
  float s = 0.f;
#pragma unroll
  for (int qq = 0; qq < 8; ++qq) s += Zpart[qq * 65536 + idx];
  RZ[idx] = 1.0f / s;
}

// ---------------- Vt *= RZ[p] in-place ----------------
__global__ __launch_bounds__(256) void k_vscale(u16* __restrict__ Vt,
                                                const float* __restrict__ RZ) {
  int t0 = blockIdx.x * 256 + threadIdx.x;
#pragma unroll 1
  for (int it = 0; it < 8; ++it) {
    int idx = t0 + it * 524288;   // 16B chunk index, 4194304 total
    int f = (idx >> 7) & 511;
    int bh = idx >> 16;
    int c = (idx & 127) ^ (f & 7);
    const float* rz = RZ + bh * 1024 + c * 8;
    float4 r0 = *(const float4*)rz;
    float4 r1 = *(const float4*)(rz + 4);
    u16* ptr = Vt + (size_t)idx * 8;
    uint4 v = *(const uint4*)ptr;
    u32 w0 = ((u32)f2bf(bf2f((u16)v.x) * r0.x)) | ((u32)f2bf(bf2f((u16)(v.x >> 16)) * r0.y) << 16);
    u32 w1 = ((u32)f2bf(bf2f((u16)v.y) * r0.z)) | ((u32)f2bf(bf2f((u16)(v.y >> 16)) * r0.w) << 16);
    u32 w2 = ((u32)f2bf(bf2f((u16)v.z) * r1.x)) | ((u32)f2bf(bf2f((u16)(v.z >> 16)) * r1.y) << 16);
    u32 w3 = ((u32)f2bf(bf2f((u16)v.w) * r1.z)) | ((u32)f2bf(bf2f((u16)(v.w >> 16)) * r1.w) << 16);
    uint4 o; o.x = w0; o.y = w1; o.z = w2; o.w = w3;
    *(uint4*)ptr = o;
  }
}

// ---------------- PV-GEMM -> out ----------------
// grid 512 (bh x 8 tiles), 512 thr. M=1024(q) N=512(f) K=1024(p), BK=64.
__global__ __launch_bounds__(512) void k_pv(const u16* __restrict__ Pt,
                                            const u16* __restrict__ Vt,
                                            float* __restrict__ out) {
  __shared__ u16 As[256 * 64];
  __shared__ u16 Bs[256 * 64];
  int vid = (blockIdx.x & 7) * 64 + (blockIdx.x >> 3);
  int bh = vid >> 3;
  int tile = vid & 7;
  int q0 = (tile >> 1) * 256, f0 = (tile & 1) * 256;
  int tid = threadIdx.x, lane = tid & 63, wv = tid >> 6;
  int l15 = lane & 15, kg = lane >> 4, l7 = lane & 7;
  int wq0 = (wv >> 2) * 128, wf0 = (wv & 3) * 64;
  const u16* Arow = Pt + (size_t)bh * 1048576 + (size_t)q0 * 1024;
  const u16* Brow = Vt + (size_t)bh * 524288 + (size_t)f0 * 1024;
  int rsub = lane >> 3, csub = (lane & 7) * 8;
  fx4 acc[8][4];
#pragma unroll
  for (int mt = 0; mt < 8; ++mt)
#pragma unroll
    for (int nt = 0; nt < 4; ++nt) acc[mt][nt] = (fx4)0.0f;

  for (int ks = 0; ks < 16; ++ks) {
    __syncthreads();
#pragma unroll
    for (int i = 0; i < 4; ++i) {
      int r = wv * 32 + i * 8;
      gll16(Arow + (size_t)(r + rsub) * 1024 + ks * 64 + csub, As + r * 64);
      gll16(Brow + (size_t)(r + rsub) * 1024 + ks * 64 + csub, Bs + r * 64);
    }
    __syncthreads();
#pragma unroll
    for (int kk = 0; kk < 2; ++kk) {
      int csw = ((kk * 4 + kg) ^ l7) * 8;
      bfx8 af[8];
#pragma unroll
      for (int mt = 0; mt < 8; ++mt)
        af[mt] = *(const bfx8*)&As[(wq0 + mt * 16 + l15) * 64 + csw];
#pragma unroll
      for (int nt = 0; nt < 4; ++nt) {
        bfx8 bf = *(const bfx8*)&Bs[(wf0 + nt * 16 + l15) * 64 + csw];
#pragma unroll
        for (int mt = 0; mt < 8; ++mt) acc[mt][nt] = mfma16(af[mt], bf, acc[mt][nt]);
      }
    }
  }
#pragma unroll
  for (int mt = 0; mt < 8; ++mt) {
    int qb_ = q0 + wq0 + mt * 16 + kg * 4;
#pragma unroll
    for (int nt = 0; nt < 4; ++nt) {
      int f = f0 + wf0 + nt * 16 + l15;
      int d = f >> 4, t = f & 15;
      size_t cb = (size_t)(bh * 32 + d) * 16384 + t;
#pragma unroll
      for (int j = 0; j < 4; ++j) out[cb + (size_t)(qb_ + j) * 16] = acc[mt][nt][j];
    }
  }
}

extern "C" void kernel_launch(void* const* d_in, const int* in_sizes, int n_in,
                              void* d_out, int out_size, void* d_ws, size_t ws_size,
                              hipStream_t stream) {
  (void)in_sizes; (void)n_in; (void)out_size; (void)ws_size;
  const float* x  = (const float*)d_in[0];
  const float* Wk = (const float*)d_in[1];
  const float* Wq = (const float*)d_in[2];
  const float* Wv = (const float*)d_in[3];
  float* out = (float*)d_out;

  u16* Kb = (u16*)d_ws;                  // [64][1024][512] bf16
  u16* Qb = Kb + 33554432;               // [64][1024][512]
  u16* Vt = Qb + 33554432;               // [64][512][1024]
  u16* Pt = Vt + 33554432;               // [64][1024][1024]
  float* Zpart = (float*)(Pt + 67108864);// [8][64][1024]
  float* RZ = Zpart + 524288;            // [64][1024]
  u16* Wbf = (u16*)(RZ + 65536);         // [3][256][256]

  k_wconv<<<96, 256, 0, stream>>>(Wk, Wq, Wv, Wbf);
  k_proj<<<1024, 256, 0, stream>>>(x, Wbf, Kb, Qb, Vt);
  k_egemm<<<1024, 512, 0, stream>>>(Qb, Kb, Pt);
  k_colsum<<<1024, 256, 0, stream>>>(Pt, Zpart);
  k_zfinal<<<256, 256, 0, stream>>>(Zpart, RZ);
  k_vscale<<<2048, 256, 0, stream>>>(Vt, RZ);
  k_pv<<<512, 512, 0, stream>>>(Pt, Vt, out);
}

// Round 2
// 399.513 us; speedup vs baseline: 1.0637x; 1.0637x over previous
//
#include <hip/hip_runtime.h>

// MultiHeadAttention: B=8, C=256, H=8, D=32, T=16, P=1024, F=D*T=512
// Pipeline:
//  k_wconv : Wk/Wq/Wv fp32 -> Wall[768][256] bf16 (chunk-swizzled by o&7)
//  k_xt    : x fp32 [b][c][n] -> Xbf [b][n(16384)][c(256)] bf16 (chunk-swizzled by n&7)
//  k_proj2 : GEMM Wall x Xbf -> Kb,Qb,Vb [bh][p][512] bf16 (swizzled), dbuf-prefetch
//  k_egemm : Pt[bh][q][p] = bf16(exp2(QK^T * log2e/sqrt(512))) + fused partial Z
//  k_zfinal: RZ[bh][p] = 1/sum_q exp
//  k_vt    : Vb [p][f] --transpose+scale by RZ[p]--> Vt [bh][f][1024] bf16 (swizzled)
//  k_pv    : out[q][f] = sum_p Pt[q,p]*Vt[f,p] -> d_out fp32
// ws usage ~322 MiB (Pt overlays Xbf, Vt overlays Qb).

typedef unsigned short u16;
typedef unsigned int u32;
typedef __attribute__((ext_vector_type(8))) short bfx8;
typedef __attribute__((ext_vector_type(4))) float fx4;

constexpr float KC1 = 1.4426950408889634f / 22.627416997969522f; // log2(e)/sqrt(512)

__device__ __forceinline__ u16 f2bf(float f) {
  u32 u = __builtin_bit_cast(u32, f);
  return (u16)((u + 0x7fffu + ((u >> 16) & 1u)) >> 16);
}
__device__ __forceinline__ float bf2f(u16 v) {
  return __builtin_bit_cast(float, (u32)v << 16);
}
__device__ __forceinline__ fx4 mfma16(bfx8 a, bfx8 b, fx4 c) {
  return __builtin_amdgcn_mfma_f32_16x16x32_bf16(a, b, c, 0, 0, 0);
}
typedef __attribute__((address_space(1))) const unsigned int* as1p;
typedef __attribute__((address_space(3))) unsigned int* as3p;
__device__ __forceinline__ void gll16(const void* g, void* l) {
  __builtin_amdgcn_global_load_lds((as1p)g, (as3p)l, 16, 0, 0);
}

// ---------------- W fp32 -> Wall bf16 swizzled ----------------
__global__ __launch_bounds__(256) void k_wconv(const float* __restrict__ Wk,
                                               const float* __restrict__ Wq,
                                               const float* __restrict__ Wv,
                                               u16* __restrict__ Wall) {
  int blk = blockIdx.x;          // 96 = 3 proj * 32
  int pr = blk >> 5;
  const float* src = (pr == 0) ? Wk : ((pr == 1) ? Wq : Wv);
  int oc = (blk & 31) * 8 + (threadIdx.x >> 5);
  int Cc = threadIdx.x & 31;
  const float4* s4 = (const float4*)(src + oc * 256 + Cc * 8);
  float4 a = s4[0], b = s4[1];
  alignas(16) u16 t[8] = {f2bf(a.x), f2bf(a.y), f2bf(a.z), f2bf(a.w),
                          f2bf(b.x), f2bf(b.y), f2bf(b.z), f2bf(b.w)};
  int o = pr * 256 + oc;
  int pos = (Cc & ~7) + ((Cc & 7) ^ (o & 7));
  *(uint4*)(Wall + o * 256 + pos * 8) = *(const uint4*)t;
}

// ---------------- x -> Xbf transpose/convert ----------------
// grid 1024 (b*128 ntiles of 128 n), 256 thr. LDS transpose, swizzled chunks.
__global__ __launch_bounds__(256) void k_xt(const float* __restrict__ x,
                                            u16* __restrict__ Xbf) {
  __shared__ u16 Xs[128 * 256]; // [n][c] bf16, 64 KiB
  int b = blockIdx.x >> 7;
  int n0 = (blockIdx.x & 127) * 128;
  int tid = threadIdx.x;
  int ng = tid & 31, cgrp = tid >> 5;
  const float* xb = x + (size_t)b * 4194304 + n0 + ng * 4;
#pragma unroll
  for (int it = 0; it < 4; ++it) {
    int Cc = cgrp + it * 8;       // c-chunk 0..31
    float4 v[8];
#pragma unroll
    for (int i = 0; i < 8; ++i)
      v[i] = *(const float4*)(xb + (size_t)(Cc * 8 + i) * 16384);
#pragma unroll
    for (int j = 0; j < 4; ++j) {
      int n = ng * 4 + j;
      alignas(16) u16 c8[8];
#pragma unroll
      for (int i = 0; i < 8; ++i) c8[i] = f2bf(((const float*)&v[i])[j]);
      int pos = (Cc & ~7) + ((Cc & 7) ^ (n & 7));
      *(uint4*)&Xs[n * 256 + pos * 8] = *(const uint4*)c8;
    }
  }
  __syncthreads();
  u16* xo = Xbf + (size_t)b * 4194304 + (size_t)n0 * 256;
#pragma unroll
  for (int it = 0; it < 16; ++it) {
    int idx = tid + it * 256;
    int n = idx >> 5, chp = idx & 31;
    uint4 v = *(const uint4*)&Xs[n * 256 + chp * 8];
    *(uint4*)&xo[(size_t)n * 256 + chp * 8] = v;
  }
}

// ---------------- fused 3-projection GEMM ----------------
// grid 1536 (=512 n-groups x 3 otiles), 512 thr, tile 256(o) x 256(n), K=256.
__global__ __launch_bounds__(512) void k_proj2(const u16* __restrict__ Xbf,
                                               const u16* __restrict__ Wall,
                                               u16* __restrict__ Kb, u16* __restrict__ Qb,
                                               u16* __restrict__ Vb) {
  __shared__ u16 As[2][16384];
  __shared__ u16 Bs[2][16384];
  int bid = blockIdx.x;
  int vid = (bid & 7) * 192 + (bid >> 3);
  int nidx = vid / 3;
  int otile = vid - nidx * 3;
  int b = nidx >> 6, ntile = nidx & 63;
  int tid = threadIdx.x, lane = tid & 63, wv = tid >> 6;
  int l15 = lane & 15, kg = lane >> 4, l7 = lane & 7;
  int wq0 = (wv >> 2) * 128, wn0 = (wv & 3) * 64;
  int rsub = lane >> 3, csub = (lane & 7) * 8;
  const u16* Ag = Wall + otile * 65536;
  const u16* Bg = Xbf + (size_t)b * 4194304 + (size_t)ntile * 65536;
  fx4 acc[8][4];
#pragma unroll
  for (int mt = 0; mt < 8; ++mt)
#pragma unroll
    for (int nt = 0; nt < 4; ++nt) acc[mt][nt] = (fx4)0.0f;

  auto STAGE = [&](int buf, int ks) {
#pragma unroll
    for (int i = 0; i < 4; ++i) {
      int r = wv * 32 + i * 8;
      gll16(Ag + (size_t)(r + rsub) * 256 + ks * 64 + csub, &As[buf][r * 64]);
      gll16(Bg + (size_t)(r + rsub) * 256 + ks * 64 + csub, &Bs[buf][r * 64]);
    }
  };
  auto COMPUTE = [&](int buf) {
#pragma unroll
    for (int kk = 0; kk < 2; ++kk) {
      int csw = ((kk * 4 + kg) ^ l7) * 8;
      bfx8 af[8];
#pragma unroll
      for (int mt = 0; mt < 8; ++mt)
        af[mt] = *(const bfx8*)&As[buf][(wq0 + mt * 16 + l15) * 64 + csw];
#pragma unroll
      for (int nt = 0; nt < 4; ++nt) {
        bfx8 bf = *(const bfx8*)&Bs[buf][(wn0 + nt * 16 + l15) * 64 + csw];
#pragma unroll
        for (int mt = 0; mt < 8; ++mt) acc[mt][nt] = mfma16(af[mt], bf, acc[mt][nt]);
      }
    }
  };

  STAGE(0, 0);
  __syncthreads();
  for (int ks = 0; ks < 4; ++ks) {
    if (ks < 3) STAGE((ks + 1) & 1, ks + 1);
    COMPUTE(ks & 1);
    __syncthreads();
  }

  u16* dst = (otile == 0) ? Kb : ((otile == 1) ? Qb : Vb);
#pragma unroll
  for (int mt = 0; mt < 8; ++mt) {
    int oc = wq0 + mt * 16 + kg * 4;
    int h = oc >> 5;
    size_t bhro = (size_t)(b * 8 + h) * 524288;
#pragma unroll
    for (int nt = 0; nt < 4; ++nt) {
      int p = ntile * 16 + (wv & 3) * 4 + nt;
      size_t ro = bhro + (size_t)p * 512;
      int p7 = p & 7;
#pragma unroll
      for (int j = 0; j < 4; ++j) {
        int f = ((oc & 31) + j) * 16 + l15;
        int ch = (f >> 3) ^ p7;
        dst[ro + ch * 8 + (f & 7)] = f2bf(acc[mt][nt][j]);
      }
    }
  }
}

// ---------------- E-GEMM + exp2 -> Pt, fused partial Z ----------------
// grid 1024 (bh x 16 tiles), 512 thr, 256x256, K=512, dbuf BK=64.
__global__ __launch_bounds__(512) void k_egemm(const u16* __restrict__ Qb,
                                               const u16* __restrict__ Kb,
                                               u16* __restrict__ Pt,
                                               float* __restrict__ Zpart) {
  __shared__ u16 As[2][16384];
  __shared__ u16 Bs[2][16384];
  int bid = blockIdx.x;
  int vid = (bid & 7) * 128 + (bid >> 3);
  int bh = vid >> 4, tile = vid & 15;
  int q0 = (tile >> 2) * 256, p0 = (tile & 3) * 256;
  int tid = threadIdx.x, lane = tid & 63, wv = tid >> 6;
  int l15 = lane & 15, kg = lane >> 4, l7 = lane & 7;
  int wq0 = (wv >> 2) * 128, wp0 = (wv & 3) * 64;
  int rsub = lane >> 3, csub = (lane & 7) * 8;
  const u16* Ag = Qb + (size_t)bh * 524288 + (size_t)q0 * 512;
  const u16* Bg = Kb + (size_t)bh * 524288 + (size_t)p0 * 512;
  fx4 acc[8][4];
#pragma unroll
  for (int mt = 0; mt < 8; ++mt)
#pragma unroll
    for (int nt = 0; nt < 4; ++nt) acc[mt][nt] = (fx4)0.0f;

  auto STAGE = [&](int buf, int ks) {
#pragma unroll
    for (int i = 0; i < 4; ++i) {
      int r = wv * 32 + i * 8;
      gll16(Ag + (size_t)(r + rsub) * 512 + ks * 64 + csub, &As[buf][r * 64]);
      gll16(Bg + (size_t)(r + rsub) * 512 + ks * 64 + csub, &Bs[buf][r * 64]);
    }
  };
  auto COMPUTE = [&](int buf) {
#pragma unroll
    for (int kk = 0; kk < 2; ++kk) {
      int csw = ((kk * 4 + kg) ^ l7) * 8;
      bfx8 af[8];
#pragma unroll
      for (int mt = 0; mt < 8; ++mt)
        af[mt] = *(const bfx8*)&As[buf][(wq0 + mt * 16 + l15) * 64 + csw];
#pragma unroll
      for (int nt = 0; nt < 4; ++nt) {
        bfx8 bf = *(const bfx8*)&Bs[buf][(wp0 + nt * 16 + l15) * 64 + csw];
#pragma unroll
        for (int mt = 0; mt < 8; ++mt) acc[mt][nt] = mfma16(af[mt], bf, acc[mt][nt]);
      }
    }
  };

  STAGE(0, 0);
  __syncthreads();
  for (int ks = 0; ks < 8; ++ks) {
    if (ks < 7) STAGE((ks + 1) & 1, ks + 1);
    COMPUTE(ks & 1);
    __syncthreads();
  }

  float zl[4] = {0.f, 0.f, 0.f, 0.f};
  size_t pbase = (size_t)bh * 1048576;
#pragma unroll
  for (int mt = 0; mt < 8; ++mt) {
    int qb_ = q0 + wq0 + mt * 16 + kg * 4;
#pragma unroll
    for (int nt = 0; nt < 4; ++nt) {
      int p = p0 + wp0 + nt * 16 + l15;
#pragma unroll
      for (int j = 0; j < 4; ++j) {
        int q = qb_ + j;
        float e = exp2f(acc[mt][nt][j] * KC1);
        zl[nt] += e;
        Pt[pbase + (size_t)q * 1024 + (((p >> 3) ^ (q & 7)) * 8 + (p & 7))] = f2bf(e);
      }
    }
  }
  // reduce partial Z over the 4 kg groups (lanes xor 16, 32), then across waves via LDS
  float* Zl = (float*)&As[0][0];
#pragma unroll
  for (int nt = 0; nt < 4; ++nt) {
    float v = zl[nt];
    v += __shfl_xor(v, 16);
    v += __shfl_xor(v, 32);
    zl[nt] = v;
  }
  if (lane < 16) {
#pragma unroll
    for (int nt = 0; nt < 4; ++nt)
      Zl[(wv >> 2) * 256 + wp0 + nt * 16 + lane] = zl[nt];
  }
  __syncthreads();
  if (tid < 256) {
    float s = Zl[tid] + Zl[256 + tid];
    Zpart[(size_t)(tile >> 2) * 65536 + (size_t)bh * 1024 + p0 + tid] = s;
  }
}

__global__ __launch_bounds__(256) void k_zfinal(const float* __restrict__ Zpart,
                                                float* __restrict__ RZ) {
  int idx = blockIdx.x * 256 + threadIdx.x; // 65536
  float s = Zpart[idx] + Zpart[65536 + idx] + Zpart[131072 + idx] + Zpart[196608 + idx];
  RZ[idx] = 1.0f / s;
}

// ---------------- Vb [p][f] -> Vt [f][p] with 1/Z scale ----------------
// grid 1024 (bh x 16 ptiles of 64 p), 256 thr, LDS [64 p][512 f].
__global__ __launch_bounds__(256) void k_vt(const u16* __restrict__ Vb,
                                            const float* __restrict__ RZ,
                                            u16* __restrict__ Vt) {
  __shared__ u16 Vl[64 * 512];
  int bh = blockIdx.x >> 4;
  int ptile = blockIdx.x & 15;
  int tid = threadIdx.x;
  const u16* src = Vb + (size_t)bh * 524288 + (size_t)ptile * 32768;
#pragma unroll
  for (int it = 0; it < 16; ++it) {
    int idx = tid + it * 256;
    int pl = idx >> 6, g = idx & 63;
    float rz = RZ[bh * 1024 + ptile * 64 + pl];
    uint4 v = *(const uint4*)&src[(size_t)pl * 512 + g * 8];
    int cf = g ^ (pl & 7);   // unswizzle: logical f-chunk
    u32 w[4] = {v.x, v.y, v.z, v.w};
    alignas(16) u16 c8[8];
#pragma unroll
    for (int i = 0; i < 4; ++i) {
      c8[2 * i]     = f2bf(bf2f((u16)w[i]) * rz);
      c8[2 * i + 1] = f2bf(bf2f((u16)(w[i] >> 16)) * rz);
    }
    *(uint4*)&Vl[pl * 512 + cf * 8] = *(const uint4*)c8;
  }
  __syncthreads();
  u16* dst = Vt + (size_t)bh * 524288;
#pragma unroll
  for (int it = 0; it < 16; ++it) {
    int f = (tid & 63) + (it & 7) * 64;
    int pc = (tid >> 6) * 2 + (it >> 3);
    int base = pc * 8 * 512 + f;
    u32 x0 = (u32)Vl[base] | ((u32)Vl[base + 512] << 16);
    u32 x1 = (u32)Vl[base + 1024] | ((u32)Vl[base + 1536] << 16);
    u32 x2 = (u32)Vl[base + 2048] | ((u32)Vl[base + 2560] << 16);
    u32 x3 = (u32)Vl[base + 3072] | ((u32)Vl[base + 3584] << 16);
    uint4 pk; pk.x = x0; pk.y = x1; pk.z = x2; pk.w = x3;
    int col = ptile * 8 + (pc ^ (f & 7));
    *(uint4*)&dst[(size_t)f * 1024 + col * 8] = pk;
  }
}

// ---------------- PV-GEMM -> out ----------------
// grid 512 (bh x 8 tiles), 512 thr, 256x256, K=1024, dbuf BK=64.
__global__ __launch_bounds__(512) void k_pv(const u16* __restrict__ Pt,
                                            const u16* __restrict__ Vt,
                                            float* __restrict__ out) {
  __shared__ u16 As[2][16384];
  __shared__ u16 Bs[2][16384];
  int bid = blockIdx.x;
  int vid = (bid & 7) * 64 + (bid >> 3);
  int bh = vid >> 3, tile = vid & 7;
  int q0 = (tile >> 1) * 256, f0 = (tile & 1) * 256;
  int tid = threadIdx.x, lane = tid & 63, wv = tid >> 6;
  int l15 = lane & 15, kg = lane >> 4, l7 = lane & 7;
  int wq0 = (wv >> 2) * 128, wf0 = (wv & 3) * 64;
  int rsub = lane >> 3, csub = (lane & 7) * 8;
  const u16* Ag = Pt + (size_t)bh * 1048576 + (size_t)q0 * 1024;
  const u16* Bg = Vt + (size_t)bh * 524288 + (size_t)f0 * 1024;
  fx4 acc[8][4];
#pragma unroll
  for (int mt = 0; mt < 8; ++mt)
#pragma unroll
    for (int nt = 0; nt < 4; ++nt) acc[mt][nt] = (fx4)0.0f;

  auto STAGE = [&](int buf, int ks) {
#pragma unroll
    for (int i = 0; i < 4; ++i) {
      int r = wv * 32 + i * 8;
      gll16(Ag + (size_t)(r + rsub) * 1024 + ks * 64 + csub, &As[buf][r * 64]);
      gll16(Bg + (size_t)(r + rsub) * 1024 + ks * 64 + csub, &Bs[buf][r * 64]);
    }
  };
  auto COMPUTE = [&](int buf) {
#pragma unroll
    for (int kk = 0; kk < 2; ++kk) {
      int csw = ((kk * 4 + kg) ^ l7) * 8;
      bfx8 af[8];
#pragma unroll
      for (int mt = 0; mt < 8; ++mt)
        af[mt] = *(const bfx8*)&As[buf][(wq0 + mt * 16 + l15) * 64 + csw];
#pragma unroll
      for (int nt = 0; nt < 4; ++nt) {
        bfx8 bf = *(const bfx8*)&Bs[buf][(wf0 + nt * 16 + l15) * 64 + csw];
#pragma unroll
        for (int mt = 0; mt < 8; ++mt) acc[mt][nt] = mfma16(af[mt], bf, acc[mt][nt]);
      }
    }
  };

  STAGE(0, 0);
  __syncthreads();
  for (int ks = 0; ks < 16; ++ks) {
    if (ks < 15) STAGE((ks + 1) & 1, ks + 1);
    COMPUTE(ks & 1);
    __syncthreads();
  }

#pragma unroll
  for (int mt = 0; mt < 8; ++mt) {
    int qb_ = q0 + wq0 + mt * 16 + kg * 4;
#pragma unroll
    for (int nt = 0; nt < 4; ++nt) {
      int f = f0 + wf0 + nt * 16 + l15;
      int d = f >> 4, t = f & 15;
      size_t cb = (size_t)(bh * 32 + d) * 16384 + t;
#pragma unroll
      for (int j = 0; j < 4; ++j) out[cb + (size_t)(qb_ + j) * 16] = acc[mt][nt][j];
    }
  }
}

extern "C" void kernel_launch(void* const* d_in, const int* in_sizes, int n_in,
                              void* d_out, int out_size, void* d_ws, size_t ws_size,
                              hipStream_t stream) {
  (void)in_sizes; (void)n_in; (void)out_size; (void)ws_size;
  const float* x  = (const float*)d_in[0];
  const float* Wk = (const float*)d_in[1];
  const float* Wq = (const float*)d_in[2];
  const float* Wv = (const float*)d_in[3];
  float* out = (float*)d_out;

  u16* Kb  = (u16*)d_ws;                  // [ 0, 64) MiB  [64 bh][1024 p][512 f]
  u16* Qb  = Kb + 33554432;               // [64,128) MiB
  u16* Vb  = Qb + 33554432;               // [128,192) MiB
  u16* Xbf = Vb + 33554432;               // [192,256) MiB [8 b][16384 n][256 c]
  u16* Pt  = Xbf;                         // [192,320) MiB (overlays dead Xbf)
  u16* Vt  = Qb;                          // [64,128) MiB  (overlays dead Qb)
  float* Zpart = (float*)(Kb + 167772160);// 320 MiB: [4][64][1024]
  float* RZ = Zpart + 262144;             // [64][1024]
  u16* Wall = (u16*)(RZ + 65536);         // [768][256]

  k_wconv<<<96, 256, 0, stream>>>(Wk, Wq, Wv, Wall);
  k_xt<<<1024, 256, 0, stream>>>(x, Xbf);
  k_proj2<<<1536, 512, 0, stream>>>(Xbf, Wall, Kb, Qb, Vb);
  k_egemm<<<1024, 512, 0, stream>>>(Qb, Kb, Pt, Zpart);
  k_zfinal<<<256, 256, 0, stream>>>(Zpart, RZ);
  k_vt<<<1024, 256, 0, stream>>>(Vb, RZ, Vt);
  k_pv<<<512, 512, 0, stream>>>(Pt, Vt, out);
}

// Round 3
// 388.966 us; speedup vs baseline: 1.0925x; 1.0271x over previous
//
#include <hip/hip_runtime.h>

// MultiHeadAttention: B=8, C=256, H=8, D=32, T=16, P=1024, F=D*T=512
// Pipeline:
//  k_wconv : Wk/Wq/Wv fp32 -> Wall[768][256] bf16 (chunk-swizzled by o&7)
//  k_xt    : x fp32 [b][c][n] -> Xbf [b][n(16384)][c(256)] bf16 (chunk-swizzled by n&7)
//  k_proj2 : GEMM Wall x Xbf -> Kb,Qb,Vb [bh][p][512] bf16 (swizzled)
//  k_egemm : Pt[bh][q][p] = bf16(exp2(QK^T * log2e/sqrt(512))) + fused partial Z
//  k_zfinal: RZ[bh][p] = 1/sum_q exp
//  k_vt    : Vb [p][f] --transpose+scale by RZ[p]--> Vt [bh][f][1024] bf16 (swizzled)
//  k_pv    : out[q][f] = sum_p Pt[q,p]*Vt[f,p] -> d_out fp32
// GEMM cores use a counted-vmcnt pipeline (T3/T4/T5): A 3-deep, B 2-deep LDS
// (160 KiB), raw s_barrier with vmcnt(4) before it (never 0 mid-loop),
// setprio(1) around the MFMA cluster, sched_barrier(0) pins against hoisting.

typedef unsigned short u16;
typedef unsigned int u32;
typedef __attribute__((ext_vector_type(8))) short bfx8;
typedef __attribute__((ext_vector_type(4))) float fx4;

constexpr float KC1 = 1.4426950408889634f / 22.627416997969522f; // log2(e)/sqrt(512)

__device__ __forceinline__ u16 f2bf(float f) {
  u32 u = __builtin_bit_cast(u32, f);
  return (u16)((u + 0x7fffu + ((u >> 16) & 1u)) >> 16);
}
__device__ __forceinline__ float bf2f(u16 v) {
  return __builtin_bit_cast(float, (u32)v << 16);
}
__device__ __forceinline__ fx4 mfma16(bfx8 a, bfx8 b, fx4 c) {
  return __builtin_amdgcn_mfma_f32_16x16x32_bf16(a, b, c, 0, 0, 0);
}
typedef __attribute__((address_space(1))) const unsigned int* as1p;
typedef __attribute__((address_space(3))) unsigned int* as3p;
__device__ __forceinline__ void gll16(const void* g, void* l) {
  __builtin_amdgcn_global_load_lds((as1p)g, (as3p)l, 16, 0, 0);
}

// ---- pipelined 256x256 GEMM core: NT K-steps of 64, row length LK (u16) ----
// As: 3 x 32 KiB (A rows 0..255 x 64), Bs: 2 x 32 KiB. acc[8][4] per thread.
template <int NT, int LK>
__device__ __forceinline__ void gemm_core(const u16* __restrict__ Ag,
                                          const u16* __restrict__ Bg,
                                          u16 (&As)[3][16384], u16 (&Bs)[2][16384],
                                          fx4 (&acc)[8][4], int wv, int lane) {
  const int l15 = lane & 15, kg = lane >> 4, l7 = lane & 7;
  const int wq0 = (wv >> 2) * 128, wn0 = (wv & 3) * 64;
  const int rsub = lane >> 3, csub = (lane & 7) * 8;

  auto stageA = [&](int buf, int ks) {
#pragma unroll
    for (int i = 0; i < 4; ++i) {
      int r = wv * 32 + i * 8;
      gll16(Ag + (size_t)(r + rsub) * LK + ks * 64 + csub, &As[buf][r * 64]);
    }
  };
  auto stageB = [&](int buf, int ks) {
#pragma unroll
    for (int i = 0; i < 4; ++i) {
      int r = wv * 32 + i * 8;
      gll16(Bg + (size_t)(r + rsub) * LK + ks * 64 + csub, &Bs[buf][r * 64]);
    }
  };
  auto comp = [&](int ab, int bb) {
#pragma unroll
    for (int kk = 0; kk < 2; ++kk) {
      int csw = ((kk * 4 + kg) ^ l7) * 8;
      bfx8 af[8];
#pragma unroll
      for (int mt = 0; mt < 8; ++mt)
        af[mt] = *(const bfx8*)&As[ab][(wq0 + mt * 16 + l15) * 64 + csw];
#pragma unroll
      for (int nt = 0; nt < 4; ++nt) {
        bfx8 bf = *(const bfx8*)&Bs[bb][(wn0 + nt * 16 + l15) * 64 + csw];
#pragma unroll
        for (int mt = 0; mt < 8; ++mt) acc[mt][nt] = mfma16(af[mt], bf, acc[mt][nt]);
      }
    }
  };

  // prologue: A0,B0,A1,B1 in flight; wait for tile 0 (8 newest still flying)
  stageA(0, 0);
  stageB(0, 0);
  stageA(1, 1);
  stageB(1, 1);
  asm volatile("s_waitcnt vmcnt(8)" ::: "memory");
  __builtin_amdgcn_s_barrier();
  __builtin_amdgcn_sched_barrier(0);

  int ca = 0;
#pragma unroll 1
  for (int t = 0; t < NT; ++t) {
    const int cb = t & 1;
    if (t + 2 < NT) {
      int ca2 = ca + 2; if (ca2 >= 3) ca2 -= 3;
      stageA(ca2, t + 2);                 // into buffer freed at t-1's barrier
    }
    __builtin_amdgcn_s_setprio(1);
    comp(ca, cb);
    __builtin_amdgcn_s_setprio(0);
    if (t + 1 < NT) {
      if (t + 2 < NT) {
        asm volatile("s_waitcnt vmcnt(4)" ::: "memory"); // A(t+1),B(t+1) landed
      } else {
        asm volatile("s_waitcnt vmcnt(0)" ::: "memory"); // drain for last step
      }
      __builtin_amdgcn_s_barrier();
      __builtin_amdgcn_sched_barrier(0);
      if (t + 2 < NT) stageB(cb, t + 2);  // into B buffer consumed this step
    }
    ca = (ca == 2) ? 0 : ca + 1;
  }
}

// ---------------- W fp32 -> Wall bf16 swizzled ----------------
__global__ __launch_bounds__(256) void k_wconv(const float* __restrict__ Wk,
                                               const float* __restrict__ Wq,
                                               const float* __restrict__ Wv,
                                               u16* __restrict__ Wall) {
  int blk = blockIdx.x;          // 96 = 3 proj * 32
  int pr = blk >> 5;
  const float* src = (pr == 0) ? Wk : ((pr == 1) ? Wq : Wv);
  int oc = (blk & 31) * 8 + (threadIdx.x >> 5);
  int Cc = threadIdx.x & 31;
  const float4* s4 = (const float4*)(src + oc * 256 + Cc * 8);
  float4 a = s4[0], b = s4[1];
  alignas(16) u16 t[8] = {f2bf(a.x), f2bf(a.y), f2bf(a.z), f2bf(a.w),
                          f2bf(b.x), f2bf(b.y), f2bf(b.z), f2bf(b.w)};
  int o = pr * 256 + oc;
  int pos = (Cc & ~7) + ((Cc & 7) ^ (o & 7));
  *(uint4*)(Wall + o * 256 + pos * 8) = *(const uint4*)t;
}

// ---------------- x -> Xbf transpose/convert ----------------
__global__ __launch_bounds__(256) void k_xt(const float* __restrict__ x,
                                            u16* __restrict__ Xbf) {
  __shared__ u16 Xs[128 * 256]; // [n][c] bf16, 64 KiB
  int b = blockIdx.x >> 7;
  int n0 = (blockIdx.x & 127) * 128;
  int tid = threadIdx.x;
  int ng = tid & 31, cgrp = tid >> 5;
  const float* xb = x + (size_t)b * 4194304 + n0 + ng * 4;
#pragma unroll
  for (int it = 0; it < 4; ++it) {
    int Cc = cgrp + it * 8;       // c-chunk 0..31
    float4 v[8];
#pragma unroll
    for (int i = 0; i < 8; ++i)
      v[i] = *(const float4*)(xb + (size_t)(Cc * 8 + i) * 16384);
#pragma unroll
    for (int j = 0; j < 4; ++j) {
      int n = ng * 4 + j;
      alignas(16) u16 c8[8];
#pragma unroll
      for (int i = 0; i < 8; ++i) c8[i] = f2bf(((const float*)&v[i])[j]);
      int pos = (Cc & ~7) + ((Cc & 7) ^ (n & 7));
      *(uint4*)&Xs[n * 256 + pos * 8] = *(const uint4*)c8;
    }
  }
  __syncthreads();
  u16* xo = Xbf + (size_t)b * 4194304 + (size_t)n0 * 256;
#pragma unroll
  for (int it = 0; it < 16; ++it) {
    int idx = tid + it * 256;
    int n = idx >> 5, chp = idx & 31;
    uint4 v = *(const uint4*)&Xs[n * 256 + chp * 8];
    *(uint4*)&xo[(size_t)n * 256 + chp * 8] = v;
  }
}

// ---------------- fused 3-projection GEMM ----------------
// grid 1536 (=512 n-groups x 3 otiles), 512 thr, tile 256(o) x 256(n), K=256.
__global__ __launch_bounds__(512) void k_proj2(const u16* __restrict__ Xbf,
                                               const u16* __restrict__ Wall,
                                               u16* __restrict__ Kb, u16* __restrict__ Qb,
                                               u16* __restrict__ Vb) {
  __shared__ u16 As[3][16384];
  __shared__ u16 Bs[2][16384];
  int bid = blockIdx.x;
  int vid = (bid & 7) * 192 + (bid >> 3);
  int nidx = vid / 3;
  int otile = vid - nidx * 3;
  int b = nidx >> 6, ntile = nidx & 63;
  int tid = threadIdx.x, lane = tid & 63, wv = tid >> 6;
  int l15 = lane & 15, kg = lane >> 4;
  int wq0 = (wv >> 2) * 128;
  const u16* Ag = Wall + otile * 65536;
  const u16* Bg = Xbf + (size_t)b * 4194304 + (size_t)ntile * 65536;
  fx4 acc[8][4];
#pragma unroll
  for (int mt = 0; mt < 8; ++mt)
#pragma unroll
    for (int nt = 0; nt < 4; ++nt) acc[mt][nt] = (fx4)0.0f;

  gemm_core<4, 256>(Ag, Bg, As, Bs, acc, wv, lane);

  u16* dst = (otile == 0) ? Kb : ((otile == 1) ? Qb : Vb);
#pragma unroll
  for (int mt = 0; mt < 8; ++mt) {
    int oc = wq0 + mt * 16 + kg * 4;
    int h = oc >> 5;
    size_t bhro = (size_t)(b * 8 + h) * 524288;
#pragma unroll
    for (int nt = 0; nt < 4; ++nt) {
      int p = ntile * 16 + (wv & 3) * 4 + nt;
      size_t ro = bhro + (size_t)p * 512;
      int p7 = p & 7;
#pragma unroll
      for (int j = 0; j < 4; ++j) {
        int f = ((oc & 31) + j) * 16 + l15;
        int ch = (f >> 3) ^ p7;
        dst[ro + ch * 8 + (f & 7)] = f2bf(acc[mt][nt][j]);
      }
    }
  }
}

// ---------------- E-GEMM + exp2 -> Pt, fused partial Z ----------------
// grid 1024 (bh x 16 tiles), 512 thr, 256x256, K=512.
__global__ __launch_bounds__(512) void k_egemm(const u16* __restrict__ Qb,
                                               const u16* __restrict__ Kb,
                                               u16* __restrict__ Pt,
                                               float* __restrict__ Zpart) {
  __shared__ u16 As[3][16384];
  __shared__ u16 Bs[2][16384];
  int bid = blockIdx.x;
  int vid = (bid & 7) * 128 + (bid >> 3);
  int bh = vid >> 4, tile = vid & 15;
  int q0 = (tile >> 2) * 256, p0 = (tile & 3) * 256;
  int tid = threadIdx.x, lane = tid & 63, wv = tid >> 6;
  int l15 = lane & 15, kg = lane >> 4;
  int wq0 = (wv >> 2) * 128, wp0 = (wv & 3) * 64;
  const u16* Ag = Qb + (size_t)bh * 524288 + (size_t)q0 * 512;
  const u16* Bg = Kb + (size_t)bh * 524288 + (size_t)p0 * 512;
  fx4 acc[8][4];
#pragma unroll
  for (int mt = 0; mt < 8; ++mt)
#pragma unroll
    for (int nt = 0; nt < 4; ++nt) acc[mt][nt] = (fx4)0.0f;

  gemm_core<8, 512>(Ag, Bg, As, Bs, acc, wv, lane);

  float zl[4] = {0.f, 0.f, 0.f, 0.f};
  size_t pbase = (size_t)bh * 1048576;
#pragma unroll
  for (int mt = 0; mt < 8; ++mt) {
    int qb_ = q0 + wq0 + mt * 16 + kg * 4;
#pragma unroll
    for (int nt = 0; nt < 4; ++nt) {
      int p = p0 + wp0 + nt * 16 + l15;
#pragma unroll
      for (int j = 0; j < 4; ++j) {
        int q = qb_ + j;
        float e = exp2f(acc[mt][nt][j] * KC1);
        zl[nt] += e;
        Pt[pbase + (size_t)q * 1024 + (((p >> 3) ^ (q & 7)) * 8 + (p & 7))] = f2bf(e);
      }
    }
  }
  // reduce partial Z over the 4 kg groups (lanes xor 16, 32), then across waves
  float* Zl = (float*)&As[0][0];  // last step read As[1]/Bs[1]; As[0] is free
#pragma unroll
  for (int nt = 0; nt < 4; ++nt) {
    float v = zl[nt];
    v += __shfl_xor(v, 16);
    v += __shfl_xor(v, 32);
    zl[nt] = v;
  }
  if (lane < 16) {
#pragma unroll
    for (int nt = 0; nt < 4; ++nt)
      Zl[(wv >> 2) * 256 + wp0 + nt * 16 + lane] = zl[nt];
  }
  __syncthreads();
  if (tid < 256) {
    float s = Zl[tid] + Zl[256 + tid];
    Zpart[(size_t)(tile >> 2) * 65536 + (size_t)bh * 1024 + p0 + tid] = s;
  }
}

__global__ __launch_bounds__(256) void k_zfinal(const float* __restrict__ Zpart,
                                                float* __restrict__ RZ) {
  int idx = blockIdx.x * 256 + threadIdx.x; // 65536
  float s = Zpart[idx] + Zpart[65536 + idx] + Zpart[131072 + idx] + Zpart[196608 + idx];
  RZ[idx] = 1.0f / s;
}

// ---------------- Vb [p][f] -> Vt [f][p] with 1/Z scale ----------------
__global__ __launch_bounds__(256) void k_vt(const u16* __restrict__ Vb,
                                            const float* __restrict__ RZ,
                                            u16* __restrict__ Vt) {
  __shared__ u16 Vl[64 * 512];
  int bh = blockIdx.x >> 4;
  int ptile = blockIdx.x & 15;
  int tid = threadIdx.x;
  const u16* src = Vb + (size_t)bh * 524288 + (size_t)ptile * 32768;
#pragma unroll
  for (int it = 0; it < 16; ++it) {
    int idx = tid + it * 256;
    int pl = idx >> 6, g = idx & 63;
    float rz = RZ[bh * 1024 + ptile * 64 + pl];
    uint4 v = *(const uint4*)&src[(size_t)pl * 512 + g * 8];
    int cf = g ^ (pl & 7);   // unswizzle: logical f-chunk
    u32 w[4] = {v.x, v.y, v.z, v.w};
    alignas(16) u16 c8[8];
#pragma unroll
    for (int i = 0; i < 4; ++i) {
      c8[2 * i]     = f2bf(bf2f((u16)w[i]) * rz);
      c8[2 * i + 1] = f2bf(bf2f((u16)(w[i] >> 16)) * rz);
    }
    *(uint4*)&Vl[pl * 512 + cf * 8] = *(const uint4*)c8;
  }
  __syncthreads();
  u16* dst = Vt + (size_t)bh * 524288;
#pragma unroll
  for (int it = 0; it < 16; ++it) {
    int f = (tid & 63) + (it & 7) * 64;
    int pc = (tid >> 6) * 2 + (it >> 3);
    int base = pc * 8 * 512 + f;
    u32 x0 = (u32)Vl[base] | ((u32)Vl[base + 512] << 16);
    u32 x1 = (u32)Vl[base + 1024] | ((u32)Vl[base + 1536] << 16);
    u32 x2 = (u32)Vl[base + 2048] | ((u32)Vl[base + 2560] << 16);
    u32 x3 = (u32)Vl[base + 3072] | ((u32)Vl[base + 3584] << 16);
    uint4 pk; pk.x = x0; pk.y = x1; pk.z = x2; pk.w = x3;
    int col = ptile * 8 + (pc ^ (f & 7));
    *(uint4*)&dst[(size_t)f * 1024 + col * 8] = pk;
  }
}

// ---------------- PV-GEMM -> out ----------------
// grid 512 (bh x 8 tiles), 512 thr, 256x256, K=1024.
__global__ __launch_bounds__(512) void k_pv(const u16* __restrict__ Pt,
                                            const u16* __restrict__ Vt,
                                            float* __restrict__ out) {
  __shared__ u16 As[3][16384];
  __shared__ u16 Bs[2][16384];
  int bid = blockIdx.x;
  int vid = (bid & 7) * 64 + (bid >> 3);
  int bh = vid >> 3, tile = vid & 7;
  int q0 = (tile >> 1) * 256, f0 = (tile & 1) * 256;
  int tid = threadIdx.x, lane = tid & 63, wv = tid >> 6;
  int l15 = lane & 15, kg = lane >> 4;
  int wq0 = (wv >> 2) * 128, wf0 = (wv & 3) * 64;
  const u16* Ag = Pt + (size_t)bh * 1048576 + (size_t)q0 * 1024;
  const u16* Bg = Vt + (size_t)bh * 524288 + (size_t)f0 * 1024;
  fx4 acc[8][4];
#pragma unroll
  for (int mt = 0; mt < 8; ++mt)
#pragma unroll
    for (int nt = 0; nt < 4; ++nt) acc[mt][nt] = (fx4)0.0f;

  gemm_core<16, 1024>(Ag, Bg, As, Bs, acc, wv, lane);

#pragma unroll
  for (int mt = 0; mt < 8; ++mt) {
    int qb_ = q0 + wq0 + mt * 16 + kg * 4;
#pragma unroll
    for (int nt = 0; nt < 4; ++nt) {
      int f = f0 + wf0 + nt * 16 + l15;
      int d = f >> 4, t = f & 15;
      size_t cb = (size_t)(bh * 32 + d) * 16384 + t;
#pragma unroll
      for (int j = 0; j < 4; ++j) out[cb + (size_t)(qb_ + j) * 16] = acc[mt][nt][j];
    }
  }
}

extern "C" void kernel_launch(void* const* d_in, const int* in_sizes, int n_in,
                              void* d_out, int out_size, void* d_ws, size_t ws_size,
                              hipStream_t stream) {
  (void)in_sizes; (void)n_in; (void)out_size; (void)ws_size;
  const float* x  = (const float*)d_in[0];
  const float* Wk = (const float*)d_in[1];
  const float* Wq = (const float*)d_in[2];
  const float* Wv = (const float*)d_in[3];
  float* out = (float*)d_out;

  u16* Kb  = (u16*)d_ws;                  // [ 0, 64) MiB  [64 bh][1024 p][512 f]
  u16* Qb  = Kb + 33554432;               // [64,128) MiB
  u16* Vb  = Qb + 33554432;               // [128,192) MiB
  u16* Xbf = Vb + 33554432;               // [192,256) MiB [8 b][16384 n][256 c]
  u16* Pt  = Xbf;                         // [192,320) MiB (overlays dead Xbf)
  u16* Vt  = Qb;                          // [64,128) MiB  (overlays dead Qb)
  float* Zpart = (float*)(Kb + 167772160);// 320 MiB: [4][64][1024]
  float* RZ = Zpart + 262144;             // [64][1024]
  u16* Wall = (u16*)(RZ + 65536);         // [768][256]

  k_wconv<<<96, 256, 0, stream>>>(Wk, Wq, Wv, Wall);
  k_xt<<<1024, 256, 0, stream>>>(x, Xbf);
  k_proj2<<<1536, 512, 0, stream>>>(Xbf, Wall, Kb, Qb, Vb);
  k_egemm<<<1024, 512, 0, stream>>>(Qb, Kb, Pt, Zpart);
  k_zfinal<<<256, 256, 0, stream>>>(Zpart, RZ);
  k_vt<<<1024, 256, 0, stream>>>(Vb, RZ, Vt);
  k_pv<<<512, 512, 0, stream>>>(Pt, Vt, out);
}

// Round 4
// 352.721 us; speedup vs baseline: 1.2048x; 1.1028x over previous
//
#include <hip/hip_runtime.h>

// MultiHeadAttention: B=8, C=256, H=8, D=32, T=16, P=1024, F=D*T=512
// Pipeline:
//  k_wconv : Wk/Wq/Wv fp32 -> Wall[768][256] bf16 (chunk-swizzled by o&7)
//  k_xt    : x fp32 [b][c][n] -> Xbf [b][n(16384)][c(256)] bf16 (chunk-swizzled by n&7)
//  k_proj2 : GEMM Wall x Xbf -> Kb,Qb,Vb [bh][p][512] bf16 (swizzled)
//  k_egemm : Pt[bh][q][p] = bf16(exp2(QK^T * log2e/sqrt(512))) + fused partial Z
//  k_zfinal: RZ[bh][p] = 1/sum_q exp
//  k_vt    : Vb [p][f] --transpose+scale by RZ[p]--> Vt [bh][f][1024] bf16 (swizzled)
//  k_pv    : out[q][f] = sum_p Pt[q,p]*Vt[f,p] -> d_out fp32
// GEMM cores: m201-style 8-phase schedule. 256x256 tile, BK=64, 8 waves
// (2M x 4N, interleaved half ownership). Per phase: ds_read subtile + stage
// one half-tile (2 x global_load_lds) + s_barrier + lgkmcnt(0) + setprio(1)
// + 16 MFMA + setprio(0) + s_barrier. vmcnt(4) only at phases 4/8.

typedef unsigned short u16;
typedef unsigned int u32;
typedef __attribute__((ext_vector_type(8))) short bfx8;
typedef __attribute__((ext_vector_type(4))) float fx4;

constexpr float KC1 = 1.4426950408889634f / 22.627416997969522f; // log2(e)/sqrt(512)

__device__ __forceinline__ u16 f2bf(float f) {
  u32 u = __builtin_bit_cast(u32, f);
  return (u16)((u + 0x7fffu + ((u >> 16) & 1u)) >> 16);
}
__device__ __forceinline__ float bf2f(u16 v) {
  return __builtin_bit_cast(float, (u32)v << 16);
}
__device__ __forceinline__ fx4 mfma16(bfx8 a, bfx8 b, fx4 c) {
  return __builtin_amdgcn_mfma_f32_16x16x32_bf16(a, b, c, 0, 0, 0);
}
typedef __attribute__((address_space(1))) const unsigned int* as1p;
typedef __attribute__((address_space(3))) unsigned int* as3p;
__device__ __forceinline__ void gll16(const void* g, void* l) {
  __builtin_amdgcn_global_load_lds((as1p)g, (as3p)l, 16, 0, 0);
}
__device__ __forceinline__ void bar_() {
  __builtin_amdgcn_s_barrier();
  __builtin_amdgcn_sched_barrier(0);
}
__device__ __forceinline__ void lg0_() {
  asm volatile("s_waitcnt lgkmcnt(0)" ::: "memory");
  __builtin_amdgcn_sched_barrier(0);
}
#define VMC4 asm volatile("s_waitcnt vmcnt(4)" ::: "memory")
#define VMC0 asm volatile("s_waitcnt vmcnt(0)" ::: "memory")

// ---- 8-phase 256x256 GEMM core. NT K-tiles of 64; row length LK (u16). ----
// lds: 128 KiB. A dbuf0 @0, A dbuf1 @16384, B dbuf0 @32768, B dbuf1 @49152.
// Halves: +h*8192 (128 rows x 64). Wave wv: wr=wv>>2 (M), wn=wv&3 (N).
// acc[mh][mt][nh][nt]: row = mh*128+wr*64+mt*16+kg*4+j, col = nh*128+wn*32+nt*16+l15.
template <int NT, int LK>
__device__ __forceinline__ void gemm8(const u16* __restrict__ Ag,
                                      const u16* __restrict__ Bg,
                                      u16* lds, fx4 (&acc)[2][4][2][2],
                                      int wv, int lane) {
  const int l15 = lane & 15, kg = lane >> 4, l7 = lane & 7;
  const int wr = wv >> 2, wn = wv & 3;
  const int rsub = lane >> 3, csub = (lane & 7) * 8;
  constexpr int A0 = 0, A1 = 16384, B0 = 32768, B1 = 49152;
  bfx8 af[4][2], bf[2][2][2];

  auto stg = [&](const u16* g, int ldsoff, int tile, int half) {
    const u16* gp = g + (size_t)(half * 128 + wv * 16 + rsub) * LK + tile * 64 + csub;
    u16* lp = lds + ldsoff + half * 8192 + wv * 1024;
    gll16(gp, lp);
    gll16(gp + (size_t)8 * LK, lp + 512);
  };
  auto LA = [&](int boff, int mh) {
    const u16* base = lds + boff + mh * 8192 + wr * 4096;
#pragma unroll
    for (int mt = 0; mt < 4; ++mt)
#pragma unroll
      for (int kk = 0; kk < 2; ++kk)
        af[mt][kk] = *(const bfx8*)(base + (mt * 16 + l15) * 64 + (((kk << 2) + kg) ^ l7) * 8);
  };
  auto LB = [&](int boff, int nh) {
    const u16* base = lds + boff + nh * 8192 + wn * 2048;
#pragma unroll
    for (int nt = 0; nt < 2; ++nt)
#pragma unroll
      for (int kk = 0; kk < 2; ++kk)
        bf[nh][nt][kk] = *(const bfx8*)(base + (nt * 16 + l15) * 64 + (((kk << 2) + kg) ^ l7) * 8);
  };
  auto MM = [&](int mh, int nh) {
    __builtin_amdgcn_s_setprio(1);
#pragma unroll
    for (int mt = 0; mt < 4; ++mt)
#pragma unroll
      for (int nt = 0; nt < 2; ++nt)
#pragma unroll
        for (int kk = 0; kk < 2; ++kk)
          acc[mh][mt][nh][nt] = mfma16(af[mt][kk], bf[nh][nt][kk], acc[mh][mt][nh][nt]);
    __builtin_amdgcn_s_setprio(0);
  };

  // prologue: t0 all 4 halves, then A-lo(t1), B-hi(t1). vmcnt(4) -> t0 landed.
  stg(Ag, A0, 0, 0); stg(Ag, A0, 0, 1);
  stg(Bg, B0, 0, 0); stg(Bg, B0, 0, 1);
  stg(Ag, A1, 1, 0); stg(Bg, B1, 1, 1);
  VMC4;
  bar_();

  constexpr int NI = NT / 2;
#pragma unroll 1
  for (int i = 0; i < NI; ++i) {
    const int t = 2 * i;
    const bool more = (i + 1 < NI);
    // ph1: Q(0,0) of tile t
    LA(A0, 0); LB(B0, 0);
    stg(Ag, A1, t + 1, 1);                  // A-hi(t+1) -> dbuf1
    bar_(); lg0_();
    MM(0, 0);
    bar_();
    // ph2: Q(0,1)
    LB(B0, 1);
    stg(Bg, B1, t + 1, 0);                  // B-lo(t+1)
    bar_(); lg0_();
    MM(0, 1);
    bar_();
    // ph3: Q(1,1)
    LA(A0, 1);
    if (more) stg(Ag, A0, t + 2, 0);        // A-lo(t+2) -> dbuf0
    bar_(); lg0_();
    MM(1, 1);
    bar_();
    // ph4: Q(1,0)  (reuses af from ph3, bf[0] from ph1)
    if (more) stg(Bg, B0, t + 2, 1);        // B-hi(t+2)
    bar_();
    MM(1, 0);
    if (more) { VMC4; } else { VMC0; }      // gate tile t+1 reads
    bar_();
    // ph5: Q(0,0) of tile t+1
    LA(A1, 0); LB(B1, 0);
    if (more) stg(Ag, A0, t + 2, 1);        // A-hi(t+2)
    bar_(); lg0_();
    MM(0, 0);
    bar_();
    // ph6: Q(0,1)
    LB(B1, 1);
    if (more) stg(Bg, B0, t + 2, 0);        // B-lo(t+2)
    bar_(); lg0_();
    MM(0, 1);
    bar_();
    // ph7: Q(1,1)
    LA(A1, 1);
    if (more) stg(Ag, A1, t + 3, 0);        // A-lo(t+3) -> dbuf1
    bar_(); lg0_();
    MM(1, 1);
    bar_();
    // ph8: Q(1,0)
    if (more) stg(Bg, B1, t + 3, 1);        // B-hi(t+3)
    bar_();
    MM(1, 0);
    if (more) { VMC4; }                     // gate tile t+2 reads
    bar_();
  }
}

// ---------------- W fp32 -> Wall bf16 swizzled ----------------
__global__ __launch_bounds__(256) void k_wconv(const float* __restrict__ Wk,
                                               const float* __restrict__ Wq,
                                               const float* __restrict__ Wv,
                                               u16* __restrict__ Wall) {
  int blk = blockIdx.x;          // 96 = 3 proj * 32
  int pr = blk >> 5;
  const float* src = (pr == 0) ? Wk : ((pr == 1) ? Wq : Wv);
  int oc = (blk & 31) * 8 + (threadIdx.x >> 5);
  int Cc = threadIdx.x & 31;
  const float4* s4 = (const float4*)(src + oc * 256 + Cc * 8);
  float4 a = s4[0], b = s4[1];
  alignas(16) u16 t[8] = {f2bf(a.x), f2bf(a.y), f2bf(a.z), f2bf(a.w),
                          f2bf(b.x), f2bf(b.y), f2bf(b.z), f2bf(b.w)};
  int o = pr * 256 + oc;
  int pos = (Cc & ~7) + ((Cc & 7) ^ (o & 7));
  *(uint4*)(Wall + o * 256 + pos * 8) = *(const uint4*)t;
}

// ---------------- x -> Xbf transpose/convert ----------------
__global__ __launch_bounds__(256) void k_xt(const float* __restrict__ x,
                                            u16* __restrict__ Xbf) {
  __shared__ u16 Xs[128 * 256]; // [n][c] bf16, 64 KiB
  int b = blockIdx.x >> 7;
  int n0 = (blockIdx.x & 127) * 128;
  int tid = threadIdx.x;
  int ng = tid & 31, cgrp = tid >> 5;
  const float* xb = x + (size_t)b * 4194304 + n0 + ng * 4;
#pragma unroll
  for (int it = 0; it < 4; ++it) {
    int Cc = cgrp + it * 8;       // c-chunk 0..31
    float4 v[8];
#pragma unroll
    for (int i = 0; i < 8; ++i)
      v[i] = *(const float4*)(xb + (size_t)(Cc * 8 + i) * 16384);
#pragma unroll
    for (int j = 0; j < 4; ++j) {
      int n = ng * 4 + j;
      alignas(16) u16 c8[8];
#pragma unroll
      for (int i = 0; i < 8; ++i) c8[i] = f2bf(((const float*)&v[i])[j]);
      int pos = (Cc & ~7) + ((Cc & 7) ^ (n & 7));
      *(uint4*)&Xs[n * 256 + pos * 8] = *(const uint4*)c8;
    }
  }
  __syncthreads();
  u16* xo = Xbf + (size_t)b * 4194304 + (size_t)n0 * 256;
#pragma unroll
  for (int it = 0; it < 16; ++it) {
    int idx = tid + it * 256;
    int n = idx >> 5, chp = idx & 31;
    uint4 v = *(const uint4*)&Xs[n * 256 + chp * 8];
    *(uint4*)&xo[(size_t)n * 256 + chp * 8] = v;
  }
}

// ---------------- fused 3-projection GEMM ----------------
// grid 1536 (=512 n-groups x 3 otiles), 512 thr, tile 256(o) x 256(n), K=256.
__global__ __launch_bounds__(512) void k_proj2(const u16* __restrict__ Xbf,
                                               const u16* __restrict__ Wall,
                                               u16* __restrict__ Kb, u16* __restrict__ Qb,
                                               u16* __restrict__ Vb) {
  __shared__ u16 lds[65536];
  int bid = blockIdx.x;
  int vid = (bid & 7) * 192 + (bid >> 3);
  int nidx = vid / 3;
  int otile = vid - nidx * 3;
  int b = nidx >> 6, ntile = nidx & 63;
  int tid = threadIdx.x, lane = tid & 63, wv = tid >> 6;
  int l15 = lane & 15, kg = lane >> 4;
  int wr = wv >> 2, wn = wv & 3;
  const u16* Ag = Wall + otile * 65536;
  const u16* Bg = Xbf + (size_t)b * 4194304 + (size_t)ntile * 65536;
  fx4 acc[2][4][2][2];
#pragma unroll
  for (int mh = 0; mh < 2; ++mh)
#pragma unroll
    for (int mt = 0; mt < 4; ++mt)
#pragma unroll
      for (int nh = 0; nh < 2; ++nh)
#pragma unroll
        for (int nt = 0; nt < 2; ++nt) acc[mh][mt][nh][nt] = (fx4)0.0f;

  gemm8<4, 256>(Ag, Bg, lds, acc, wv, lane);

  u16* dst = (otile == 0) ? Kb : ((otile == 1) ? Qb : Vb);
#pragma unroll
  for (int mh = 0; mh < 2; ++mh)
#pragma unroll
    for (int mt = 0; mt < 4; ++mt) {
      int o = mh * 128 + wr * 64 + mt * 16 + kg * 4;
      int h = o >> 5;
      size_t bhro = (size_t)(b * 8 + h) * 524288;
#pragma unroll
      for (int nh = 0; nh < 2; ++nh)
#pragma unroll
        for (int nt = 0; nt < 2; ++nt) {
          int p = ntile * 16 + nh * 8 + wn * 2 + nt;
          size_t ro = bhro + (size_t)p * 512;
          int p7 = p & 7;
#pragma unroll
          for (int j = 0; j < 4; ++j) {
            int f = ((o & 31) + j) * 16 + l15;
            int ch = (f >> 3) ^ p7;
            dst[ro + ch * 8 + (f & 7)] = f2bf(acc[mh][mt][nh][nt][j]);
          }
        }
    }
}

// ---------------- E-GEMM + exp2 -> Pt, fused partial Z ----------------
// grid 1024 (bh x 16 tiles), 512 thr, 256x256, K=512.
__global__ __launch_bounds__(512) void k_egemm(const u16* __restrict__ Qb,
                                               const u16* __restrict__ Kb,
                                               u16* __restrict__ Pt,
                                               float* __restrict__ Zpart) {
  __shared__ u16 lds[65536];
  int bid = blockIdx.x;
  int vid = (bid & 7) * 128 + (bid >> 3);
  int bh = vid >> 4, tile = vid & 15;
  int q0 = (tile >> 2) * 256, p0 = (tile & 3) * 256;
  int tid = threadIdx.x, lane = tid & 63, wv = tid >> 6;
  int l15 = lane & 15, kg = lane >> 4;
  int wr = wv >> 2, wn = wv & 3;
  const u16* Ag = Qb + (size_t)bh * 524288 + (size_t)q0 * 512;
  const u16* Bg = Kb + (size_t)bh * 524288 + (size_t)p0 * 512;
  fx4 acc[2][4][2][2];
#pragma unroll
  for (int mh = 0; mh < 2; ++mh)
#pragma unroll
    for (int mt = 0; mt < 4; ++mt)
#pragma unroll
      for (int nh = 0; nh < 2; ++nh)
#pragma unroll
        for (int nt = 0; nt < 2; ++nt) acc[mh][mt][nh][nt] = (fx4)0.0f;

  gemm8<8, 512>(Ag, Bg, lds, acc, wv, lane);

  float zl[2][2] = {{0.f, 0.f}, {0.f, 0.f}};
  size_t pbase = (size_t)bh * 1048576;
#pragma unroll
  for (int mh = 0; mh < 2; ++mh)
#pragma unroll
    for (int mt = 0; mt < 4; ++mt) {
      int qb_ = q0 + mh * 128 + wr * 64 + mt * 16 + kg * 4;
#pragma unroll
      for (int nh = 0; nh < 2; ++nh)
#pragma unroll
        for (int nt = 0; nt < 2; ++nt) {
          int p = p0 + nh * 128 + wn * 32 + nt * 16 + l15;
#pragma unroll
          for (int j = 0; j < 4; ++j) {
            int q = qb_ + j;
            float e = exp2f(acc[mh][mt][nh][nt][j] * KC1);
            zl[nh][nt] += e;
            Pt[pbase + (size_t)q * 1024 + (((p >> 3) ^ (q & 7)) * 8 + (p & 7))] = f2bf(e);
          }
        }
    }
  // reduce partial Z over kg (lanes xor 16,32), then across the two wr groups
  float* Zl = (float*)lds;
#pragma unroll
  for (int nh = 0; nh < 2; ++nh)
#pragma unroll
    for (int nt = 0; nt < 2; ++nt) {
      float v = zl[nh][nt];
      v += __shfl_xor(v, 16);
      v += __shfl_xor(v, 32);
      zl[nh][nt] = v;
    }
  __syncthreads();
  if (lane < 16) {
#pragma unroll
    for (int nh = 0; nh < 2; ++nh)
#pragma unroll
      for (int nt = 0; nt < 2; ++nt)
        Zl[wr * 256 + nh * 128 + wn * 32 + nt * 16 + lane] = zl[nh][nt];
  }
  __syncthreads();
  if (tid < 256) {
    float s = Zl[tid] + Zl[256 + tid];
    Zpart[(size_t)(tile >> 2) * 65536 + (size_t)bh * 1024 + p0 + tid] = s;
  }
}

__global__ __launch_bounds__(256) void k_zfinal(const float* __restrict__ Zpart,
                                                float* __restrict__ RZ) {
  int idx = blockIdx.x * 256 + threadIdx.x; // 65536
  float s = Zpart[idx] + Zpart[65536 + idx] + Zpart[131072 + idx] + Zpart[196608 + idx];
  RZ[idx] = 1.0f / s;
}

// ---------------- Vb [p][f] -> Vt [f][p] with 1/Z scale ----------------
__global__ __launch_bounds__(256) void k_vt(const u16* __restrict__ Vb,
                                            const float* __restrict__ RZ,
                                            u16* __restrict__ Vt) {
  __shared__ u16 Vl[64 * 512];
  int bh = blockIdx.x >> 4;
  int ptile = blockIdx.x & 15;
  int tid = threadIdx.x;
  const u16* src = Vb + (size_t)bh * 524288 + (size_t)ptile * 32768;
#pragma unroll
  for (int it = 0; it < 16; ++it) {
    int idx = tid + it * 256;
    int pl = idx >> 6, g = idx & 63;
    float rz = RZ[bh * 1024 + ptile * 64 + pl];
    uint4 v = *(const uint4*)&src[(size_t)pl * 512 + g * 8];
    int cf = g ^ (pl & 7);   // unswizzle: logical f-chunk
    u32 w[4] = {v.x, v.y, v.z, v.w};
    alignas(16) u16 c8[8];
#pragma unroll
    for (int i = 0; i < 4; ++i) {
      c8[2 * i]     = f2bf(bf2f((u16)w[i]) * rz);
      c8[2 * i + 1] = f2bf(bf2f((u16)(w[i] >> 16)) * rz);
    }
    *(uint4*)&Vl[pl * 512 + cf * 8] = *(const uint4*)c8;
  }
  __syncthreads();
  u16* dst = Vt + (size_t)bh * 524288;
#pragma unroll
  for (int it = 0; it < 16; ++it) {
    int f = (tid & 63) + (it & 7) * 64;
    int pc = (tid >> 6) * 2 + (it >> 3);
    int base = pc * 8 * 512 + f;
    u32 x0 = (u32)Vl[base] | ((u32)Vl[base + 512] << 16);
    u32 x1 = (u32)Vl[base + 1024] | ((u32)Vl[base + 1536] << 16);
    u32 x2 = (u32)Vl[base + 2048] | ((u32)Vl[base + 2560] << 16);
    u32 x3 = (u32)Vl[base + 3072] | ((u32)Vl[base + 3584] << 16);
    uint4 pk; pk.x = x0; pk.y = x1; pk.z = x2; pk.w = x3;
    int col = ptile * 8 + (pc ^ (f & 7));
    *(uint4*)&dst[(size_t)f * 1024 + col * 8] = pk;
  }
}

// ---------------- PV-GEMM -> out ----------------
// grid 512 (bh x 8 tiles), 512 thr, 256x256, K=1024.
__global__ __launch_bounds__(512) void k_pv(const u16* __restrict__ Pt,
                                            const u16* __restrict__ Vt,
                                            float* __restrict__ out) {
  __shared__ u16 lds[65536];
  int bid = blockIdx.x;
  int vid = (bid & 7) * 64 + (bid >> 3);
  int bh = vid >> 3, tile = vid & 7;
  int q0 = (tile >> 1) * 256, f0 = (tile & 1) * 256;
  int tid = threadIdx.x, lane = tid & 63, wv = tid >> 6;
  int l15 = lane & 15, kg = lane >> 4;
  int wr = wv >> 2, wn = wv & 3;
  const u16* Ag = Pt + (size_t)bh * 1048576 + (size_t)q0 * 1024;
  const u16* Bg = Vt + (size_t)bh * 524288 + (size_t)f0 * 1024;
  fx4 acc[2][4][2][2];
#pragma unroll
  for (int mh = 0; mh < 2; ++mh)
#pragma unroll
    for (int mt = 0; mt < 4; ++mt)
#pragma unroll
      for (int nh = 0; nh < 2; ++nh)
#pragma unroll
        for (int nt = 0; nt < 2; ++nt) acc[mh][mt][nh][nt] = (fx4)0.0f;

  gemm8<16, 1024>(Ag, Bg, lds, acc, wv, lane);

#pragma unroll
  for (int mh = 0; mh < 2; ++mh)
#pragma unroll
    for (int mt = 0; mt < 4; ++mt) {
      int qb_ = q0 + mh * 128 + wr * 64 + mt * 16 + kg * 4;
#pragma unroll
      for (int nh = 0; nh < 2; ++nh)
#pragma unroll
        for (int nt = 0; nt < 2; ++nt) {
          int f = f0 + nh * 128 + wn * 32 + nt * 16 + l15;
          int d = f >> 4, t = f & 15;
          size_t cb = (size_t)(bh * 32 + d) * 16384 + t;
#pragma unroll
          for (int j = 0; j < 4; ++j) out[cb + (size_t)(qb_ + j) * 16] = acc[mh][mt][nh][nt][j];
        }
    }
}

extern "C" void kernel_launch(void* const* d_in, const int* in_sizes, int n_in,
                              void* d_out, int out_size, void* d_ws, size_t ws_size,
                              hipStream_t stream) {
  (void)in_sizes; (void)n_in; (void)out_size; (void)ws_size;
  const float* x  = (const float*)d_in[0];
  const float* Wk = (const float*)d_in[1];
  const float* Wq = (const float*)d_in[2];
  const float* Wv = (const float*)d_in[3];
  float* out = (float*)d_out;

  u16* Kb  = (u16*)d_ws;                  // [ 0, 64) MiB  [64 bh][1024 p][512 f]
  u16* Qb  = Kb + 33554432;               // [64,128) MiB
  u16* Vb  = Qb + 33554432;               // [128,192) MiB
  u16* Xbf = Vb + 33554432;               // [192,256) MiB [8 b][16384 n][256 c]
  u16* Pt  = Xbf;                         // [192,320) MiB (overlays dead Xbf)
  u16* Vt  = Qb;                          // [64,128) MiB  (overlays dead Qb)
  float* Zpart = (float*)(Kb + 167772160);// 320 MiB: [4][64][1024]
  float* RZ = Zpart + 262144;             // [64][1024]
  u16* Wall = (u16*)(RZ + 65536);         // [768][256]

  k_wconv<<<96, 256, 0, stream>>>(Wk, Wq, Wv, Wall);
  k_xt<<<1024, 256, 0, stream>>>(x, Xbf);
  k_proj2<<<1536, 512, 0, stream>>>(Xbf, Wall, Kb, Qb, Vb);
  k_egemm<<<1024, 512, 0, stream>>>(Qb, Kb, Pt, Zpart);
  k_zfinal<<<256, 256, 0, stream>>>(Zpart, RZ);
  k_vt<<<1024, 256, 0, stream>>>(Vb, RZ, Vt);
  k_pv<<<512, 512, 0, stream>>>(Pt, Vt, out);
}

// Round 5
// 351.468 us; speedup vs baseline: 1.2091x; 1.0036x over previous
//
#include <hip/hip_runtime.h>

// MultiHeadAttention: B=8, C=256, H=8, D=32, T=16, P=1024, F=D*T=512
// Pipeline:
//  k_wconv : Wk/Wq/Wv fp32 -> Wall[768][256] bf16 (chunk-swizzled by o&7)
//  k_xt    : x fp32 [b][c][n] -> Xbf [b][n(16384)][c(256)] bf16 (chunk-swizzled by n&7)
//  k_proj2 : GEMM Wall x Xbf -> Kb,Qb,Vb [bh][p][512] bf16 (swizzled)
//  k_egemm : Pt[bh][q][p] = bf16(exp2(QK^T * log2e/sqrt(512))) + fused partial Z
//  k_zfinal: RZ[bh][p] = 1/sum_q exp
//  k_vt    : Vb [p][f] --transpose+scale by RZ[p]--> Vt [bh][f][1024] bf16 (swizzled)
//  k_pv    : out[q][f] = sum_p Pt[q,p]*Vt[f,p] -> d_out fp32
// GEMM cores: 8-phase schedule, RELAXED intra-phase scheduling: no explicit
// lgkmcnt (compiler emits partial waits from data deps -> ds_read/MFMA
// overlap within the phase); sched_barrier(0) only at phase ends and after
// counted-vmcnt waits (write-protection ledger). vmcnt(4) at phases 4/8 only.

typedef unsigned short u16;
typedef unsigned int u32;
typedef __attribute__((ext_vector_type(8))) short bfx8;
typedef __attribute__((ext_vector_type(4))) float fx4;

constexpr float KC1 = 1.4426950408889634f / 22.627416997969522f; // log2(e)/sqrt(512)

__device__ __forceinline__ u16 f2bf(float f) {
  u32 u = __builtin_bit_cast(u32, f);
  return (u16)((u + 0x7fffu + ((u >> 16) & 1u)) >> 16);
}
__device__ __forceinline__ float bf2f(u16 v) {
  return __builtin_bit_cast(float, (u32)v << 16);
}
__device__ __forceinline__ fx4 mfma16(bfx8 a, bfx8 b, fx4 c) {
  return __builtin_amdgcn_mfma_f32_16x16x32_bf16(a, b, c, 0, 0, 0);
}
typedef __attribute__((address_space(1))) const unsigned int* as1p;
typedef __attribute__((address_space(3))) unsigned int* as3p;
__device__ __forceinline__ void gll16(const void* g, void* l) {
  __builtin_amdgcn_global_load_lds((as1p)g, (as3p)l, 16, 0, 0);
}
__device__ __forceinline__ void midbar_() {      // plain wave-alignment barrier
  __builtin_amdgcn_s_barrier();
}
__device__ __forceinline__ void pend_() {        // phase end: pin the ledger
  __builtin_amdgcn_s_barrier();
  __builtin_amdgcn_sched_barrier(0);
}
#define VMC4 do { asm volatile("s_waitcnt vmcnt(4)" ::: "memory"); \
                  __builtin_amdgcn_sched_barrier(0); } while (0)
#define VMC0 do { asm volatile("s_waitcnt vmcnt(0)" ::: "memory"); \
                  __builtin_amdgcn_sched_barrier(0); } while (0)

// ---- 8-phase 256x256 GEMM core. NT K-tiles of 64; row length LK (u16). ----
// lds: 128 KiB. A dbuf0 @0, A dbuf1 @16384, B dbuf0 @32768, B dbuf1 @49152.
// Halves: +h*8192 (128 rows x 64). Wave wv: wr=wv>>2 (M), wn=wv&3 (N).
// acc[mh][mt][nh][nt]: row = mh*128+wr*64+mt*16+kg*4+j, col = nh*128+wn*32+nt*16+l15.
template <int NT, int LK>
__device__ __forceinline__ void gemm8(const u16* __restrict__ Ag,
                                      const u16* __restrict__ Bg,
                                      u16* lds, fx4 (&acc)[2][4][2][2],
                                      int wv, int lane) {
  const int l15 = lane & 15, kg = lane >> 4, l7 = lane & 7;
  const int wr = wv >> 2, wn = wv & 3;
  const int rsub = lane >> 3, csub = (lane & 7) * 8;
  constexpr int A0 = 0, A1 = 16384, B0 = 32768, B1 = 49152;
  bfx8 af[4][2], bf[2][2][2];

  auto stg = [&](const u16* g, int ldsoff, int tile, int half) {
    const u16* gp = g + (size_t)(half * 128 + wv * 16 + rsub) * LK + tile * 64 + csub;
    u16* lp = lds + ldsoff + half * 8192 + wv * 1024;
    gll16(gp, lp);
    gll16(gp + (size_t)8 * LK, lp + 512);
  };
  auto LA = [&](int boff, int mh) {
    const u16* base = lds + boff + mh * 8192 + wr * 4096;
#pragma unroll
    for (int mt = 0; mt < 4; ++mt)
#pragma unroll
      for (int kk = 0; kk < 2; ++kk)
        af[mt][kk] = *(const bfx8*)(base + (mt * 16 + l15) * 64 + (((kk << 2) + kg) ^ l7) * 8);
  };
  auto LB = [&](int boff, int nh) {
    const u16* base = lds + boff + nh * 8192 + wn * 2048;
#pragma unroll
    for (int nt = 0; nt < 2; ++nt)
#pragma unroll
      for (int kk = 0; kk < 2; ++kk)
        bf[nh][nt][kk] = *(const bfx8*)(base + (nt * 16 + l15) * 64 + (((kk << 2) + kg) ^ l7) * 8);
  };
  auto MM = [&](int mh, int nh) {
    __builtin_amdgcn_s_setprio(1);
#pragma unroll
    for (int mt = 0; mt < 4; ++mt)
#pragma unroll
      for (int nt = 0; nt < 2; ++nt)
#pragma unroll
        for (int kk = 0; kk < 2; ++kk)
          acc[mh][mt][nh][nt] = mfma16(af[mt][kk], bf[nh][nt][kk], acc[mh][mt][nh][nt]);
    __builtin_amdgcn_s_setprio(0);
  };

  // prologue: t0 all 4 halves, then A-lo(t1), B-hi(t1). vmcnt(4) -> t0 landed.
  stg(Ag, A0, 0, 0); stg(Ag, A0, 0, 1);
  stg(Bg, B0, 0, 0); stg(Bg, B0, 0, 1);
  stg(Ag, A1, 1, 0); stg(Bg, B1, 1, 1);
  VMC4;
  pend_();

  constexpr int NI = NT / 2;
#pragma unroll 1
  for (int i = 0; i < NI; ++i) {
    const int t = 2 * i;
    const bool more = (i + 1 < NI);
    // ph1: Q(0,0) of tile t
    LA(A0, 0); LB(B0, 0);
    stg(Ag, A1, t + 1, 1);                  // A-hi(t+1) -> dbuf1
    midbar_();
    MM(0, 0);
    pend_();
    // ph2: Q(0,1)
    LB(B0, 1);
    stg(Bg, B1, t + 1, 0);                  // B-lo(t+1)
    midbar_();
    MM(0, 1);
    pend_();
    // ph3: Q(1,1)
    LA(A0, 1);
    if (more) stg(Ag, A0, t + 2, 0);        // A-lo(t+2) -> dbuf0
    midbar_();
    MM(1, 1);
    pend_();
    // ph4: Q(1,0)  (reuses af from ph3, bf[0] from ph1)
    if (more) stg(Bg, B0, t + 2, 1);        // B-hi(t+2)
    midbar_();
    MM(1, 0);
    if (more) { VMC4; } else { VMC0; }      // gate tile t+1 reads
    pend_();
    // ph5: Q(0,0) of tile t+1
    LA(A1, 0); LB(B1, 0);
    if (more) stg(Ag, A0, t + 2, 1);        // A-hi(t+2)
    midbar_();
    MM(0, 0);
    pend_();
    // ph6: Q(0,1)
    LB(B1, 1);
    if (more) stg(Bg, B0, t + 2, 0);        // B-lo(t+2)
    midbar_();
    MM(0, 1);
    pend_();
    // ph7: Q(1,1)
    LA(A1, 1);
    if (more) stg(Ag, A1, t + 3, 0);        // A-lo(t+3) -> dbuf1
    midbar_();
    MM(1, 1);
    pend_();
    // ph8: Q(1,0)
    if (more) stg(Bg, B1, t + 3, 1);        // B-hi(t+3)
    midbar_();
    MM(1, 0);
    if (more) { VMC4; }                     // gate tile t+2 reads
    pend_();
  }
}

// ---------------- W fp32 -> Wall bf16 swizzled ----------------
__global__ __launch_bounds__(256) void k_wconv(const float* __restrict__ Wk,
                                               const float* __restrict__ Wq,
                                               const float* __restrict__ Wv,
                                               u16* __restrict__ Wall) {
  int blk = blockIdx.x;          // 96 = 3 proj * 32
  int pr = blk >> 5;
  const float* src = (pr == 0) ? Wk : ((pr == 1) ? Wq : Wv);
  int oc = (blk & 31) * 8 + (threadIdx.x >> 5);
  int Cc = threadIdx.x & 31;
  const float4* s4 = (const float4*)(src + oc * 256 + Cc * 8);
  float4 a = s4[0], b = s4[1];
  alignas(16) u16 t[8] = {f2bf(a.x), f2bf(a.y), f2bf(a.z), f2bf(a.w),
                          f2bf(b.x), f2bf(b.y), f2bf(b.z), f2bf(b.w)};
  int o = pr * 256 + oc;
  int pos = (Cc & ~7) + ((Cc & 7) ^ (o & 7));
  *(uint4*)(Wall + o * 256 + pos * 8) = *(const uint4*)t;
}

// ---------------- x -> Xbf transpose/convert ----------------
__global__ __launch_bounds__(256) void k_xt(const float* __restrict__ x,
                                            u16* __restrict__ Xbf) {
  __shared__ u16 Xs[128 * 256]; // [n][c] bf16, 64 KiB
  int b = blockIdx.x >> 7;
  int n0 = (blockIdx.x & 127) * 128;
  int tid = threadIdx.x;
  int ng = tid & 31, cgrp = tid >> 5;
  const float* xb = x + (size_t)b * 4194304 + n0 + ng * 4;
#pragma unroll
  for (int it = 0; it < 4; ++it) {
    int Cc = cgrp + it * 8;       // c-chunk 0..31
    float4 v[8];
#pragma unroll
    for (int i = 0; i < 8; ++i)
      v[i] = *(const float4*)(xb + (size_t)(Cc * 8 + i) * 16384);
#pragma unroll
    for (int j = 0; j < 4; ++j) {
      int n = ng * 4 + j;
      alignas(16) u16 c8[8];
#pragma unroll
      for (int i = 0; i < 8; ++i) c8[i] = f2bf(((const float*)&v[i])[j]);
      int pos = (Cc & ~7) + ((Cc & 7) ^ (n & 7));
      *(uint4*)&Xs[n * 256 + pos * 8] = *(const uint4*)c8;
    }
  }
  __syncthreads();
  u16* xo = Xbf + (size_t)b * 4194304 + (size_t)n0 * 256;
#pragma unroll
  for (int it = 0; it < 16; ++it) {
    int idx = tid + it * 256;
    int n = idx >> 5, chp = idx & 31;
    uint4 v = *(const uint4*)&Xs[n * 256 + chp * 8];
    *(uint4*)&xo[(size_t)n * 256 + chp * 8] = v;
  }
}

// ---------------- fused 3-projection GEMM ----------------
// grid 1536 (=512 n-groups x 3 otiles), 512 thr, tile 256(o) x 256(n), K=256.
__global__ __launch_bounds__(512) void k_proj2(const u16* __restrict__ Xbf,
                                               const u16* __restrict__ Wall,
                                               u16* __restrict__ Kb, u16* __restrict__ Qb,
                                               u16* __restrict__ Vb) {
  __shared__ u16 lds[65536];
  int bid = blockIdx.x;
  int vid = (bid & 7) * 192 + (bid >> 3);
  int nidx = vid / 3;
  int otile = vid - nidx * 3;
  int b = nidx >> 6, ntile = nidx & 63;
  int tid = threadIdx.x, lane = tid & 63, wv = tid >> 6;
  int l15 = lane & 15, kg = lane >> 4;
  int wr = wv >> 2, wn = wv & 3;
  const u16* Ag = Wall + otile * 65536;
  const u16* Bg = Xbf + (size_t)b * 4194304 + (size_t)ntile * 65536;
  fx4 acc[2][4][2][2];
#pragma unroll
  for (int mh = 0; mh < 2; ++mh)
#pragma unroll
    for (int mt = 0; mt < 4; ++mt)
#pragma unroll
      for (int nh = 0; nh < 2; ++nh)
#pragma unroll
        for (int nt = 0; nt < 2; ++nt) acc[mh][mt][nh][nt] = (fx4)0.0f;

  gemm8<4, 256>(Ag, Bg, lds, acc, wv, lane);

  u16* dst = (otile == 0) ? Kb : ((otile == 1) ? Qb : Vb);
#pragma unroll
  for (int mh = 0; mh < 2; ++mh)
#pragma unroll
    for (int mt = 0; mt < 4; ++mt) {
      int o = mh * 128 + wr * 64 + mt * 16 + kg * 4;
      int h = o >> 5;
      size_t bhro = (size_t)(b * 8 + h) * 524288;
#pragma unroll
      for (int nh = 0; nh < 2; ++nh)
#pragma unroll
        for (int nt = 0; nt < 2; ++nt) {
          int p = ntile * 16 + nh * 8 + wn * 2 + nt;
          size_t ro = bhro + (size_t)p * 512;
          int p7 = p & 7;
#pragma unroll
          for (int j = 0; j < 4; ++j) {
            int f = ((o & 31) + j) * 16 + l15;
            int ch = (f >> 3) ^ p7;
            dst[ro + ch * 8 + (f & 7)] = f2bf(acc[mh][mt][nh][nt][j]);
          }
        }
    }
}

// ---------------- E-GEMM + exp2 -> Pt, fused partial Z ----------------
// grid 1024 (bh x 16 tiles), 512 thr, 256x256, K=512.
__global__ __launch_bounds__(512) void k_egemm(const u16* __restrict__ Qb,
                                               const u16* __restrict__ Kb,
                                               u16* __restrict__ Pt,
                                               float* __restrict__ Zpart) {
  __shared__ u16 lds[65536];
  int bid = blockIdx.x;
  int vid = (bid & 7) * 128 + (bid >> 3);
  int bh = vid >> 4, tile = vid & 15;
  int q0 = (tile >> 2) * 256, p0 = (tile & 3) * 256;
  int tid = threadIdx.x, lane = tid & 63, wv = tid >> 6;
  int l15 = lane & 15, kg = lane >> 4;
  int wr = wv >> 2, wn = wv & 3;
  const u16* Ag = Qb + (size_t)bh * 524288 + (size_t)q0 * 512;
  const u16* Bg = Kb + (size_t)bh * 524288 + (size_t)p0 * 512;
  fx4 acc[2][4][2][2];
#pragma unroll
  for (int mh = 0; mh < 2; ++mh)
#pragma unroll
    for (int mt = 0; mt < 4; ++mt)
#pragma unroll
      for (int nh = 0; nh < 2; ++nh)
#pragma unroll
        for (int nt = 0; nt < 2; ++nt) acc[mh][mt][nh][nt] = (fx4)0.0f;

  gemm8<8, 512>(Ag, Bg, lds, acc, wv, lane);

  float zl[2][2] = {{0.f, 0.f}, {0.f, 0.f}};
  size_t pbase = (size_t)bh * 1048576;
#pragma unroll
  for (int mh = 0; mh < 2; ++mh)
#pragma unroll
    for (int mt = 0; mt < 4; ++mt) {
      int qb_ = q0 + mh * 128 + wr * 64 + mt * 16 + kg * 4;
#pragma unroll
      for (int nh = 0; nh < 2; ++nh)
#pragma unroll
        for (int nt = 0; nt < 2; ++nt) {
          int p = p0 + nh * 128 + wn * 32 + nt * 16 + l15;
#pragma unroll
          for (int j = 0; j < 4; ++j) {
            int q = qb_ + j;
            float e = exp2f(acc[mh][mt][nh][nt][j] * KC1);
            zl[nh][nt] += e;
            Pt[pbase + (size_t)q * 1024 + (((p >> 3) ^ (q & 7)) * 8 + (p & 7))] = f2bf(e);
          }
        }
    }
  // reduce partial Z over kg (lanes xor 16,32), then across the two wr groups
  float* Zl = (float*)lds;
#pragma unroll
  for (int nh = 0; nh < 2; ++nh)
#pragma unroll
    for (int nt = 0; nt < 2; ++nt) {
      float v = zl[nh][nt];
      v += __shfl_xor(v, 16);
      v += __shfl_xor(v, 32);
      zl[nh][nt] = v;
    }
  __syncthreads();
  if (lane < 16) {
#pragma unroll
    for (int nh = 0; nh < 2; ++nh)
#pragma unroll
      for (int nt = 0; nt < 2; ++nt)
        Zl[wr * 256 + nh * 128 + wn * 32 + nt * 16 + lane] = zl[nh][nt];
  }
  __syncthreads();
  if (tid < 256) {
    float s = Zl[tid] + Zl[256 + tid];
    Zpart[(size_t)(tile >> 2) * 65536 + (size_t)bh * 1024 + p0 + tid] = s;
  }
}

__global__ __launch_bounds__(256) void k_zfinal(const float* __restrict__ Zpart,
                                                float* __restrict__ RZ) {
  int idx = blockIdx.x * 256 + threadIdx.x; // 65536
  float s = Zpart[idx] + Zpart[65536 + idx] + Zpart[131072 + idx] + Zpart[196608 + idx];
  RZ[idx] = 1.0f / s;
}

// ---------------- Vb [p][f] -> Vt [f][p] with 1/Z scale ----------------
__global__ __launch_bounds__(256) void k_vt(const u16* __restrict__ Vb,
                                            const float* __restrict__ RZ,
                                            u16* __restrict__ Vt) {
  __shared__ u16 Vl[64 * 512];
  int bh = blockIdx.x >> 4;
  int ptile = blockIdx.x & 15;
  int tid = threadIdx.x;
  const u16* src = Vb + (size_t)bh * 524288 + (size_t)ptile * 32768;
#pragma unroll
  for (int it = 0; it < 16; ++it) {
    int idx = tid + it * 256;
    int pl = idx >> 6, g = idx & 63;
    float rz = RZ[bh * 1024 + ptile * 64 + pl];
    uint4 v = *(const uint4*)&src[(size_t)pl * 512 + g * 8];
    int cf = g ^ (pl & 7);   // unswizzle: logical f-chunk
    u32 w[4] = {v.x, v.y, v.z, v.w};
    alignas(16) u16 c8[8];
#pragma unroll
    for (int i = 0; i < 4; ++i) {
      c8[2 * i]     = f2bf(bf2f((u16)w[i]) * rz);
      c8[2 * i + 1] = f2bf(bf2f((u16)(w[i] >> 16)) * rz);
    }
    *(uint4*)&Vl[pl * 512 + cf * 8] = *(const uint4*)c8;
  }
  __syncthreads();
  u16* dst = Vt + (size_t)bh * 524288;
#pragma unroll
  for (int it = 0; it < 16; ++it) {
    int f = (tid & 63) + (it & 7) * 64;
    int pc = (tid >> 6) * 2 + (it >> 3);
    int base = pc * 8 * 512 + f;
    u32 x0 = (u32)Vl[base] | ((u32)Vl[base + 512] << 16);
    u32 x1 = (u32)Vl[base + 1024] | ((u32)Vl[base + 1536] << 16);
    u32 x2 = (u32)Vl[base + 2048] | ((u32)Vl[base + 2560] << 16);
    u32 x3 = (u32)Vl[base + 3072] | ((u32)Vl[base + 3584] << 16);
    uint4 pk; pk.x = x0; pk.y = x1; pk.z = x2; pk.w = x3;
    int col = ptile * 8 + (pc ^ (f & 7));
    *(uint4*)&dst[(size_t)f * 1024 + col * 8] = pk;
  }
}

// ---------------- PV-GEMM -> out ----------------
// grid 512 (bh x 8 tiles), 512 thr, 256x256, K=1024.
__global__ __launch_bounds__(512) void k_pv(const u16* __restrict__ Pt,
                                            const u16* __restrict__ Vt,
                                            float* __restrict__ out) {
  __shared__ u16 lds[65536];
  int bid = blockIdx.x;
  int vid = (bid & 7) * 64 + (bid >> 3);
  int bh = vid >> 3, tile = vid & 7;
  int q0 = (tile >> 1) * 256, f0 = (tile & 1) * 256;
  int tid = threadIdx.x, lane = tid & 63, wv = tid >> 6;
  int l15 = lane & 15, kg = lane >> 4;
  int wr = wv >> 2, wn = wv & 3;
  const u16* Ag = Pt + (size_t)bh * 1048576 + (size_t)q0 * 1024;
  const u16* Bg = Vt + (size_t)bh * 524288 + (size_t)f0 * 1024;
  fx4 acc[2][4][2][2];
#pragma unroll
  for (int mh = 0; mh < 2; ++mh)
#pragma unroll
    for (int mt = 0; mt < 4; ++mt)
#pragma unroll
      for (int nh = 0; nh < 2; ++nh)
#pragma unroll
        for (int nt = 0; nt < 2; ++nt) acc[mh][mt][nh][nt] = (fx4)0.0f;

  gemm8<16, 1024>(Ag, Bg, lds, acc, wv, lane);

#pragma unroll
  for (int mh = 0; mh < 2; ++mh)
#pragma unroll
    for (int mt = 0; mt < 4; ++mt) {
      int qb_ = q0 + mh * 128 + wr * 64 + mt * 16 + kg * 4;
#pragma unroll
      for (int nh = 0; nh < 2; ++nh)
#pragma unroll
        for (int nt = 0; nt < 2; ++nt) {
          int f = f0 + nh * 128 + wn * 32 + nt * 16 + l15;
          int d = f >> 4, t = f & 15;
          size_t cb = (size_t)(bh * 32 + d) * 16384 + t;
#pragma unroll
          for (int j = 0; j < 4; ++j) out[cb + (size_t)(qb_ + j) * 16] = acc[mh][mt][nh][nt][j];
        }
    }
}

extern "C" void kernel_launch(void* const* d_in, const int* in_sizes, int n_in,
                              void* d_out, int out_size, void* d_ws, size_t ws_size,
                              hipStream_t stream) {
  (void)in_sizes; (void)n_in; (void)out_size; (void)ws_size;
  const float* x  = (const float*)d_in[0];
  const float* Wk = (const float*)d_in[1];
  const float* Wq = (const float*)d_in[2];
  const float* Wv = (const float*)d_in[3];
  float* out = (float*)d_out;

  u16* Kb  = (u16*)d_ws;                  // [ 0, 64) MiB  [64 bh][1024 p][512 f]
  u16* Qb  = Kb + 33554432;               // [64,128) MiB
  u16* Vb  = Qb + 33554432;               // [128,192) MiB
  u16* Xbf = Vb + 33554432;               // [192,256) MiB [8 b][16384 n][256 c]
  u16* Pt  = Xbf;                         // [192,320) MiB (overlays dead Xbf)
  u16* Vt  = Qb;                          // [64,128) MiB  (overlays dead Qb)
  float* Zpart = (float*)(Kb + 167772160);// 320 MiB: [4][64][1024]
  float* RZ = Zpart + 262144;             // [64][1024]
  u16* Wall = (u16*)(RZ + 65536);         // [768][256]

  k_wconv<<<96, 256, 0, stream>>>(Wk, Wq, Wv, Wall);
  k_xt<<<1024, 256, 0, stream>>>(x, Xbf);
  k_proj2<<<1536, 512, 0, stream>>>(Xbf, Wall, Kb, Qb, Vb);
  k_egemm<<<1024, 512, 0, stream>>>(Qb, Kb, Pt, Zpart);
  k_zfinal<<<256, 256, 0, stream>>>(Zpart, RZ);
  k_vt<<<1024, 256, 0, stream>>>(Vb, RZ, Vt);
  k_pv<<<512, 512, 0, stream>>>(Pt, Vt, out);
}